// Round 1
// baseline (4731.738 us; speedup 1.0000x reference)
//
#include <hip/hip_runtime.h>
#include <math.h>

#define NB 4
#define NWIN 121
#define NBOX (NWIN*NWIN)   /* 14641 */
#define NKEEP 50
#define HWD 256
#define DIM 128
#define WINSZ 16
#define HEADS 8
#define DH 64
#define NTOK 256
#define NWTOT (NB*NKEEP)   /* 200 */

/* ws layout (float units) */
#define OFF_ENT   0          /* 65536 floats */
#define OFF_SCORE 65536      /* 58564 floats */
#define OFF_KEEP  124100     /* 400 ints */
#define OFF_CNT   131072     /* 262144 floats */
#define OFF_TOKS  393216     /* 200*256*128 = 6553600 floats */
#define WS_FLOATS (OFF_TOKS + (size_t)NWTOT*NTOK*DIM)

__global__ void k_entropy(const float* __restrict__ prob, float* __restrict__ ent) {
  int idx = blockIdx.x * 256 + threadIdx.x;          /* 65536 total */
  int b = idx >> 14, p = idx & 16383;
  float p0 = prob[(size_t)(b * 2) * 16384 + p];
  float p1 = prob[(size_t)(b * 2 + 1) * 16384 + p];
  ent[idx] = -(p0 * log2f(p0 + 1e-10f) + p1 * log2f(p1 + 1e-10f));
}

__global__ void k_score(const float* __restrict__ ent, const float* __restrict__ fw,
                        float* __restrict__ sc) {
  int gid = blockIdx.x * 256 + threadIdx.x;
  if (gid >= NB * NBOX) return;
  int b = gid / NBOX, rem = gid % NBOX;
  int oy = rem / NWIN, ox = rem % NWIN;
  const float* e = ent + b * 16384 + oy * 128 + ox;
  float s = 0.f;
#pragma unroll
  for (int r = 0; r < 8; ++r)
#pragma unroll
    for (int c = 0; c < 8; ++c)
      s += e[r * 128 + c] * fw[r * 8 + c];
  sc[gid] = s * (1.0f / 64.0f);
}

__global__ void k_nms(const float* __restrict__ scores, int* __restrict__ keep) {
  __shared__ float sc[NBOX];
  __shared__ float wbv[16];
  __shared__ int wbi[16];
  __shared__ int sel;
  int b = blockIdx.x, t = threadIdx.x;
  for (int e = t; e < NBOX; e += 1024) sc[e] = scores[b * NBOX + e];
  __syncthreads();
  for (int k = 0; k < NKEEP; ++k) {
    float bv = -INFINITY; int bi = 0x7fffffff;
    for (int e = t; e < NBOX; e += 1024) {
      float v = sc[e];
      if (v > bv || (v == bv && e < bi)) { bv = v; bi = e; }
    }
#pragma unroll
    for (int off = 32; off; off >>= 1) {
      float ov = __shfl_down(bv, off, 64);
      int   oi = __shfl_down(bi, off, 64);
      if (ov > bv || (ov == bv && oi < bi)) { bv = ov; bi = oi; }
    }
    if ((t & 63) == 0) { wbv[t >> 6] = bv; wbi[t >> 6] = bi; }
    __syncthreads();
    if (t == 0) {
      float fv = wbv[0]; int fi = wbi[0];
      for (int wv = 1; wv < 16; ++wv)
        if (wbv[wv] > fv || (wbv[wv] == fv && wbi[wv] < fi)) { fv = wbv[wv]; fi = wbi[wv]; }
      sel = fi;
      keep[(b * NKEEP + k) * 2 + 0] = 2 * (fi / NWIN);  /* sy */
      keep[(b * NKEEP + k) * 2 + 1] = 2 * (fi % NWIN);  /* sx */
    }
    __syncthreads();
    int fi = sel;
    int Iy = fi / NWIN, Ix = fi % NWIN;
    for (int e = t; e < NBOX; e += 1024) {
      int ey = e / NWIN, ex = e % NWIN;
      int adx = ex > Ix ? ex - Ix : Ix - ex;
      int ady = ey > Iy ? ey - Iy : Iy - ey;
      float iw = fmaxf((float)(15 - 2 * adx), 0.0f);
      float ih = fmaxf((float)(15 - 2 * ady), 0.0f);
      float inter = iw * ih;
      float iou = inter / (450.0f - inter);
      if (!(iou <= 0.2f)) sc[e] = -INFINITY;
    }
    __syncthreads();
  }
}

__global__ void k_toks(const float* __restrict__ x, const int* __restrict__ keep,
                       float* __restrict__ toks, float* __restrict__ cnt) {
  int w = blockIdx.x;
  int b = w / NKEEP;
  int sy = keep[w * 2 + 0], sx = keep[w * 2 + 1];
  int tid = threadIdx.x;
  int ch = tid & 127, th = tid >> 7;
  const float* xb = x + (size_t)b * 65536 * DIM;
  for (int it = 0; it < 128; ++it) {
    int tk = it * 2 + th;
    int i = tk >> 4, j = tk & 15;
    float offy = (i + 0.5f) * 0.9375f;
    float offx = (j + 0.5f) * 0.9375f;
    int li = (int)offy, lj = (int)offx;
    float fy = offy - (float)li, fx = offx - (float)lj;
    const float* p = xb + ((size_t)((sy + li) * HWD + (sx + lj))) * DIM + ch;
    float v00 = p[0], v01 = p[DIM], v10 = p[HWD * DIM], v11 = p[HWD * DIM + DIM];
    float w00 = (1.f - fy) * (1.f - fx), w01 = (1.f - fy) * fx;
    float w10 = fy * (1.f - fx), w11 = fy * fx;
    toks[((size_t)w * NTOK + tk) * DIM + ch] = w00 * v00 + w01 * v01 + w10 * v10 + w11 * v11;
    if (ch == 0) atomicAdd(&cnt[b * 65536 + (sy + i) * HWD + (sx + j)], 1.0f);
  }
}

__global__ __launch_bounds__(256, 2) void k_att(
    const float* __restrict__ toks, const float* __restrict__ wqkv,
    const float* __restrict__ wout, const float* __restrict__ bout,
    const int* __restrict__ keep, float* __restrict__ outacc) {
  __shared__ float kt[64][66];
  __shared__ float vt[64][66];
  int blk = blockIdx.x;
  int w = blk >> 3, h = blk & 7;
  int n = threadIdx.x;                 /* query row 0..255 */
  const float* tw = toks + (size_t)w * NTOK * DIM;

  /* ---- q = toks_row @ Wq^T, scaled ---- */
  float q[64];
#pragma unroll
  for (int d = 0; d < 64; ++d) q[d] = 0.f;
  const float* Wq = wqkv + (size_t)(h * 64) * DIM;
  for (int cc = 0; cc < DIM; cc += 16) {
    float t16[16];
#pragma unroll
    for (int c = 0; c < 16; ++c) t16[c] = tw[(size_t)n * DIM + cc + c];
#pragma unroll
    for (int d = 0; d < 64; ++d) {
      const float* wr = Wq + d * DIM + cc;
#pragma unroll
      for (int c = 0; c < 16; ++c) q[d] = fmaf(t16[c], wr[c], q[d]);
    }
  }
#pragma unroll
  for (int d = 0; d < 64; ++d) q[d] *= 0.125f;

  /* ---- flash attention over 4 key tiles of 64 ---- */
  float o[64];
#pragma unroll
  for (int d = 0; d < 64; ++d) o[d] = 0.f;
  float mrun = -INFINITY, lrun = 0.f;
  int mm = n & 63, dq = n >> 6;
  const float* Wk = wqkv + (size_t)(512 + h * 64 + dq * 16) * DIM;
  const float* Wv = wqkv + (size_t)(1024 + h * 64 + dq * 16) * DIM;

  for (int tile = 0; tile < 4; ++tile) {
    __syncthreads();   /* protect kt/vt vs previous tile readers */
    int mg = tile * 64 + mm;
    float kacc[16], vacc[16];
#pragma unroll
    for (int d = 0; d < 16; ++d) { kacc[d] = 0.f; vacc[d] = 0.f; }
    for (int cc = 0; cc < DIM; cc += 16) {
      float t16[16];
#pragma unroll
      for (int c = 0; c < 16; ++c) t16[c] = tw[(size_t)mg * DIM + cc + c];
#pragma unroll
      for (int d = 0; d < 16; ++d) {
        const float* wkr = Wk + d * DIM + cc;
        const float* wvr = Wv + d * DIM + cc;
#pragma unroll
        for (int c = 0; c < 16; ++c) {
          kacc[d] = fmaf(t16[c], wkr[c], kacc[d]);
          vacc[d] = fmaf(t16[c], wvr[c], vacc[d]);
        }
      }
    }
#pragma unroll
    for (int d = 0; d < 16; ++d) { kt[mm][dq * 16 + d] = kacc[d]; vt[mm][dq * 16 + d] = vacc[d]; }
    __syncthreads();

    for (int mc = 0; mc < 64; mc += 16) {
      float s16[16];
#pragma unroll
      for (int i = 0; i < 16; ++i) {
        float acc = 0.f;
#pragma unroll
        for (int d = 0; d < 64; ++d) acc = fmaf(q[d], kt[mc + i][d], acc);
        s16[i] = acc;
      }
      float cmax = s16[0];
#pragma unroll
      for (int i = 1; i < 16; ++i) cmax = fmaxf(cmax, s16[i]);
      float mnew = fmaxf(mrun, cmax);
      float corr = expf(mrun - mnew);
      float psum = 0.f;
#pragma unroll
      for (int i = 0; i < 16; ++i) { s16[i] = expf(s16[i] - mnew); psum += s16[i]; }
      lrun = lrun * corr + psum;
      mrun = mnew;
#pragma unroll
      for (int d = 0; d < 64; ++d) {
        float od = o[d] * corr;
#pragma unroll
        for (int i = 0; i < 16; ++i) od = fmaf(s16[i], vt[mc + i][d], od);
        o[d] = od;
      }
    }
  }
  float inv = 1.f / lrun;
#pragma unroll
  for (int d = 0; d < 64; ++d) o[d] *= inv;

  /* ---- head-partial projection + scatter ---- */
  int b = w / NKEEP;
  int sy = keep[w * 2 + 0], sx = keep[w * 2 + 1];
  int i = n >> 4, j = n & 15;
  size_t obase = (((size_t)b * 65536) + (size_t)(sy + i) * HWD + (sx + j)) * DIM;
  for (int cbi = 0; cbi < 4; ++cbi) {
    int cb = ((cbi + h) & 3) * 32;   /* stagger chunks across heads to cut atomic contention */
    float acc[32];
#pragma unroll
    for (int c = 0; c < 32; ++c) acc[c] = (h == 0) ? bout[cb + c] : 0.f;
#pragma unroll 4
    for (int c = 0; c < 32; ++c) {
      const float* wr = wout + (size_t)(cb + c) * 512 + h * 64;
      float a = acc[c];
#pragma unroll
      for (int d = 0; d < 64; ++d) a = fmaf(o[d], wr[d], a);
      acc[c] = a;
    }
#pragma unroll
    for (int c = 0; c < 32; ++c) atomicAdd(&outacc[obase + cb + c], acc[c]);
  }
}

__global__ void k_final(const float* __restrict__ x, const float* __restrict__ cnt,
                        float* __restrict__ out) {
  size_t gid = (size_t)blockIdx.x * 256 + threadIdx.x;  /* 33.5M */
  size_t pix = gid >> 7;
  float c = cnt[pix];
  out[gid] = x[gid] + out[gid] / (c + 1e-10f);
}

extern "C" void kernel_launch(void* const* d_in, const int* in_sizes, int n_in,
                              void* d_out, int out_size, void* d_ws, size_t ws_size,
                              hipStream_t stream) {
  const float* x    = (const float*)d_in[0];
  const float* prob = (const float*)d_in[1];
  const float* fixw = (const float*)d_in[2];
  const float* wqkv = (const float*)d_in[3];
  const float* wout = (const float*)d_in[4];
  const float* bout = (const float*)d_in[5];
  float* out = (float*)d_out;
  float* ws  = (float*)d_ws;
  if (ws_size < WS_FLOATS * sizeof(float)) return;  /* need ~27.8 MB scratch */

  float* ent  = ws + OFF_ENT;
  float* sc   = ws + OFF_SCORE;
  int*   keep = (int*)(ws + OFF_KEEP);
  float* cnt  = ws + OFF_CNT;
  float* toks = ws + OFF_TOKS;

  hipMemsetAsync(out, 0, (size_t)out_size * sizeof(float), stream);
  hipMemsetAsync(cnt, 0, (size_t)NB * 65536 * sizeof(float), stream);
  k_entropy<<<256, 256, 0, stream>>>(prob, ent);
  k_score<<<(NB * NBOX + 255) / 256, 256, 0, stream>>>(ent, fixw, sc);
  k_nms<<<NB, 1024, 0, stream>>>(sc, keep);
  k_toks<<<NWTOT, 256, 0, stream>>>(x, keep, toks, cnt);
  k_att<<<NWTOT * HEADS, 256, 0, stream>>>(toks, wqkv, wout, bout, keep, out);
  k_final<<<(NB * 65536 * DIM) / 256, 256, 0, stream>>>(x, cnt, out);
}

// Round 2
// 802.053 us; speedup vs baseline: 5.8995x; 5.8995x over previous
//
#include <hip/hip_runtime.h>
#include <math.h>

#define NB 4
#define NWIN 121
#define NBOX (NWIN*NWIN)   /* 14641 */
#define NKEEP 50
#define HWD 256
#define DIM 128
#define HEADS 8
#define NTOK 256
#define NWTOT (NB*NKEEP)   /* 200 */

/* ws layout (float units) */
#define OFF_ENT   0          /* 65536 */
#define OFF_SCORE 65536      /* 58564 */
#define OFF_KEEP  124160     /* 400 ints = 100 floats */
#define OFF_CNT   131072     /* 262144 */
#define OFF_WQKV  393216     /* 196608 ushort = 98304 f */
#define OFF_WOUT  491520     /* 65536 ushort = 32768 f */
#define OFF_TOKBF 524288     /* 6553600 ushort = 3276800 f */
#define WS_FLOATS 3801088

typedef __attribute__((ext_vector_type(8))) short short8;
typedef __attribute__((ext_vector_type(4))) short short4v;
typedef __attribute__((ext_vector_type(4))) float f32x4;

static __device__ __forceinline__ unsigned short f2bf(float f) {
  union { float f; unsigned u; } v; v.f = f;
  unsigned r = (v.u + 0x7fffu + ((v.u >> 16) & 1u)) >> 16;
  return (unsigned short)r;
}
static __device__ __forceinline__ short4v pk4(f32x4 a) {
  short4v r;
  r[0] = (short)f2bf(a[0]); r[1] = (short)f2bf(a[1]);
  r[2] = (short)f2bf(a[2]); r[3] = (short)f2bf(a[3]);
  return r;
}
static __device__ __forceinline__ short8 ld8_lds(const unsigned short* p) {
  short4v a = *(const short4v*)p;
  short4v b = *(const short4v*)(p + 4);
  short8 r;
  r[0]=a[0]; r[1]=a[1]; r[2]=a[2]; r[3]=a[3];
  r[4]=b[0]; r[5]=b[1]; r[6]=b[2]; r[7]=b[3];
  return r;
}
static __device__ __forceinline__ short8 ld8_g(const unsigned short* p) {
  return *(const short8*)p;   /* 16B-aligned global */
}

__global__ void k_entropy(const float* __restrict__ prob, float* __restrict__ ent) {
  int idx = blockIdx.x * 256 + threadIdx.x;
  int b = idx >> 14, p = idx & 16383;
  float p0 = prob[(size_t)(b * 2) * 16384 + p];
  float p1 = prob[(size_t)(b * 2 + 1) * 16384 + p];
  ent[idx] = -(p0 * log2f(p0 + 1e-10f) + p1 * log2f(p1 + 1e-10f));
}

__global__ void k_score(const float* __restrict__ ent, const float* __restrict__ fw,
                        float* __restrict__ sc) {
  int gid = blockIdx.x * 256 + threadIdx.x;
  if (gid >= NB * NBOX) return;
  int b = gid / NBOX, rem = gid % NBOX;
  int oy = rem / NWIN, ox = rem % NWIN;
  const float* e = ent + b * 16384 + oy * 128 + ox;
  float s = 0.f;
#pragma unroll
  for (int r = 0; r < 8; ++r)
#pragma unroll
    for (int c = 0; c < 8; ++c)
      s += e[r * 128 + c] * fw[r * 8 + c];
  sc[gid] = s * (1.0f / 64.0f);
}

__global__ void k_nms(const float* __restrict__ scores, int* __restrict__ keep) {
  __shared__ float sc[NBOX];
  __shared__ float wbv[16];
  __shared__ int wbi[16];
  __shared__ int sel;
  int b = blockIdx.x, t = threadIdx.x;
  for (int e = t; e < NBOX; e += 1024) sc[e] = scores[b * NBOX + e];
  __syncthreads();
  for (int k = 0; k < NKEEP; ++k) {
    float bv = -INFINITY; int bi = 0x7fffffff;
    for (int e = t; e < NBOX; e += 1024) {
      float v = sc[e];
      if (v > bv || (v == bv && e < bi)) { bv = v; bi = e; }
    }
#pragma unroll
    for (int off = 32; off; off >>= 1) {
      float ov = __shfl_down(bv, off, 64);
      int   oi = __shfl_down(bi, off, 64);
      if (ov > bv || (ov == bv && oi < bi)) { bv = ov; bi = oi; }
    }
    if ((t & 63) == 0) { wbv[t >> 6] = bv; wbi[t >> 6] = bi; }
    __syncthreads();
    if (t == 0) {
      float fv = wbv[0]; int fi = wbi[0];
      for (int wv2 = 1; wv2 < 16; ++wv2)
        if (wbv[wv2] > fv || (wbv[wv2] == fv && wbi[wv2] < fi)) { fv = wbv[wv2]; fi = wbi[wv2]; }
      sel = fi;
      keep[(b * NKEEP + k) * 2 + 0] = 2 * (fi / NWIN);  /* sy */
      keep[(b * NKEEP + k) * 2 + 1] = 2 * (fi % NWIN);  /* sx */
    }
    __syncthreads();
    int fi = sel;
    int Iy = fi / NWIN, Ix = fi % NWIN;
    for (int e = t; e < NBOX; e += 1024) {
      int ey = e / NWIN, ex = e % NWIN;
      int adx = ex > Ix ? ex - Ix : Ix - ex;
      int ady = ey > Iy ? ey - Iy : Iy - ey;
      float iw = fmaxf((float)(15 - 2 * adx), 0.0f);
      float ih = fmaxf((float)(15 - 2 * ady), 0.0f);
      float inter = iw * ih;
      float iou = inter / (450.0f - inter);
      if (!(iou <= 0.2f)) sc[e] = -INFINITY;
    }
    __syncthreads();
  }
}

__global__ void k_wcvt(const float* __restrict__ wqkv, const float* __restrict__ wout,
                       unsigned short* __restrict__ wqkv_bf, unsigned short* __restrict__ wout_bf) {
  int i = blockIdx.x * 256 + threadIdx.x;
  if (i < 196608) wqkv_bf[i] = f2bf(wqkv[i]);
  int j = i - 196608;
  if (j >= 0 && j < 65536) wout_bf[j] = f2bf(wout[j]);
}

__global__ void k_toks(const float* __restrict__ x, const int* __restrict__ keep,
                       unsigned short* __restrict__ tokbf, float* __restrict__ cnt) {
  int w = blockIdx.x;
  int b = w / NKEEP;
  int sy = keep[w * 2 + 0], sx = keep[w * 2 + 1];
  int tid = threadIdx.x;
  int ch = tid & 127, th = tid >> 7;
  const float* xb = x + (size_t)b * 65536 * DIM;
  for (int it = 0; it < 128; ++it) {
    int tk = it * 2 + th;
    int i = tk >> 4, j = tk & 15;
    float offy = (i + 0.5f) * 0.9375f;
    float offx = (j + 0.5f) * 0.9375f;
    int li = (int)offy, lj = (int)offx;
    float fy = offy - (float)li, fx = offx - (float)lj;
    const float* p = xb + ((size_t)((sy + li) * HWD + (sx + lj))) * DIM + ch;
    float v00 = p[0], v01 = p[DIM], v10 = p[HWD * DIM], v11 = p[HWD * DIM + DIM];
    float w00 = (1.f - fy) * (1.f - fx), w01 = (1.f - fy) * fx;
    float w10 = fy * (1.f - fx), w11 = fy * fx;
    tokbf[((size_t)w * NTOK + tk) * DIM + ch] = f2bf(w00 * v00 + w01 * v01 + w10 * v10 + w11 * v11);
    if (ch == 0) atomicAdd(&cnt[b * 65536 + (sy + i) * HWD + (sx + j)], 1.0f);
  }
}

/* LDS map (bytes):
   tok_lds  [256][132] bf16 : 0      .. 67584
   per-wave scratch (9216 B x 8 waves) at 67584:
     QK = Q[64][68] | Kt[32][68] | P[64][36]   (first 4608 B; Q spills into VT region, ok)
     VT = [64][36]                              (next 4608 B)
   Oall [64][516] bf16 overlays the whole scratch region (66048 <= 73728) */
__global__ __launch_bounds__(512, 2) void k_attn(
    const unsigned short* __restrict__ tokbf,
    const unsigned short* __restrict__ wqkv,
    const unsigned short* __restrict__ wout,
    const float* __restrict__ bout,
    const int* __restrict__ keep,
    float* __restrict__ out) {
  __shared__ __align__(16) char smem[141312];
  unsigned short* tok_lds = (unsigned short*)smem;          /* [256][132] */
  char* scr = smem + 67584;
  const int tid = threadIdx.x;
  const int wv = tid >> 6, ln = tid & 63;
  const int lo = ln & 15, hi = ln >> 4;
  const int win = blockIdx.x;
  const int h = wv;
  unsigned short* QK = (unsigned short*)(scr + wv * 9216);
  unsigned short* VT = (unsigned short*)(scr + wv * 9216 + 4608);
  unsigned short* P  = QK;
  unsigned short* Oall = (unsigned short*)scr;              /* [64][516] */

  /* stage toks: 32768 bf16 */
  const unsigned short* tw = tokbf + (size_t)win * NTOK * DIM;
  for (int it = 0; it < 8; ++it) {
    int idx = it * 4096 + tid * 8;
    int r = idx >> 7, c = idx & 127;
    *(short4v*)&tok_lds[r * 132 + c]     = *(const short4v*)&tw[idx];
    *(short4v*)&tok_lds[r * 132 + c + 4] = *(const short4v*)&tw[idx + 4];
  }
  __syncthreads();

  const int sy = keep[win * 2 + 0], sx = keep[win * 2 + 1];
  const int bidx = win / NKEEP;
  const float bias = bout[wv * 16 + lo];

  for (int p = 0; p < 4; ++p) {
    if (p) __syncthreads();   /* protect Oall reads of prev pass vs Q writes */
    const int qbase = p * 64;

    /* ---- Q-GEMM (transposed): A=Wq rows=d, B=toks cols=q -> D col=q, row=d ---- */
    f32x4 qacc[4][4];
#pragma unroll
    for (int mf = 0; mf < 4; ++mf)
#pragma unroll
      for (int nf = 0; nf < 4; ++nf) qacc[mf][nf] = (f32x4){0.f,0.f,0.f,0.f};
#pragma unroll
    for (int kf = 0; kf < 4; ++kf) {
      short8 aw[4], bt[4];
#pragma unroll
      for (int mf = 0; mf < 4; ++mf)
        aw[mf] = ld8_g(wqkv + (size_t)(h * 64 + mf * 16 + lo) * 128 + kf * 32 + hi * 8);
#pragma unroll
      for (int nf = 0; nf < 4; ++nf)
        bt[nf] = ld8_lds(&tok_lds[(qbase + nf * 16 + lo) * 132 + kf * 32 + hi * 8]);
#pragma unroll
      for (int mf = 0; mf < 4; ++mf)
#pragma unroll
        for (int nf = 0; nf < 4; ++nf)
          qacc[mf][nf] = __builtin_amdgcn_mfma_f32_16x16x32_bf16(aw[mf], bt[nf], qacc[mf][nf], 0, 0, 0);
    }
#pragma unroll
    for (int mf = 0; mf < 4; ++mf)
#pragma unroll
      for (int nf = 0; nf < 4; ++nf) {
        f32x4 s = qacc[mf][nf] * 0.125f;
        *(short4v*)&QK[(nf * 16 + lo) * 68 + mf * 16 + hi * 4] = pk4(s);  /* Q[q][d] */
      }
    short8 Qb[4][2];
#pragma unroll
    for (int nf = 0; nf < 4; ++nf)
#pragma unroll
      for (int kf = 0; kf < 2; ++kf)
        Qb[nf][kf] = ld8_lds(&QK[(nf * 16 + lo) * 68 + kf * 32 + hi * 8]);

    f32x4 Ot[4][4];   /* O^T frags: [mf(d)][nf(q)] */
#pragma unroll
    for (int mf = 0; mf < 4; ++mf)
#pragma unroll
      for (int nf = 0; nf < 4; ++nf) Ot[mf][nf] = (f32x4){0.f,0.f,0.f,0.f};
    float mrow[4] = {-INFINITY, -INFINITY, -INFINITY, -INFINITY};
    float lrow[4] = {0.f, 0.f, 0.f, 0.f};

    for (int ch = 0; ch < 8; ++ch) {
      const int kb = ch * 32;
      /* K-GEMM (transposed): A=Wk rows=d, B=toks cols=key -> Kt[key][d] */
      f32x4 kacc[4][2];
#pragma unroll
      for (int mf = 0; mf < 4; ++mf)
#pragma unroll
        for (int nf = 0; nf < 2; ++nf) kacc[mf][nf] = (f32x4){0.f,0.f,0.f,0.f};
#pragma unroll
      for (int kf = 0; kf < 4; ++kf) {
        short8 aw[4], bt[2];
#pragma unroll
        for (int mf = 0; mf < 4; ++mf)
          aw[mf] = ld8_g(wqkv + (size_t)(512 + h * 64 + mf * 16 + lo) * 128 + kf * 32 + hi * 8);
#pragma unroll
        for (int nf = 0; nf < 2; ++nf)
          bt[nf] = ld8_lds(&tok_lds[(kb + nf * 16 + lo) * 132 + kf * 32 + hi * 8]);
#pragma unroll
        for (int mf = 0; mf < 4; ++mf)
#pragma unroll
          for (int nf = 0; nf < 2; ++nf)
            kacc[mf][nf] = __builtin_amdgcn_mfma_f32_16x16x32_bf16(aw[mf], bt[nf], kacc[mf][nf], 0, 0, 0);
      }
#pragma unroll
      for (int mf = 0; mf < 4; ++mf)
#pragma unroll
        for (int nf = 0; nf < 2; ++nf)
          *(short4v*)&QK[(nf * 16 + lo) * 68 + mf * 16 + hi * 4] = pk4(kacc[mf][nf]);

      /* V-GEMM (straight): A=toks rows=key, B=Wv cols=d -> VT[d][key] */
      f32x4 vacc[2][4];
#pragma unroll
      for (int mf = 0; mf < 2; ++mf)
#pragma unroll
        for (int nf = 0; nf < 4; ++nf) vacc[mf][nf] = (f32x4){0.f,0.f,0.f,0.f};
#pragma unroll
      for (int kf = 0; kf < 4; ++kf) {
        short8 at[2], bw[4];
#pragma unroll
        for (int mf = 0; mf < 2; ++mf)
          at[mf] = ld8_lds(&tok_lds[(kb + mf * 16 + lo) * 132 + kf * 32 + hi * 8]);
#pragma unroll
        for (int nf = 0; nf < 4; ++nf)
          bw[nf] = ld8_g(wqkv + (size_t)(1024 + h * 64 + nf * 16 + lo) * 128 + kf * 32 + hi * 8);
#pragma unroll
        for (int mf = 0; mf < 2; ++mf)
#pragma unroll
          for (int nf = 0; nf < 4; ++nf)
            vacc[mf][nf] = __builtin_amdgcn_mfma_f32_16x16x32_bf16(at[mf], bw[nf], vacc[mf][nf], 0, 0, 0);
      }
#pragma unroll
      for (int mf = 0; mf < 2; ++mf)
#pragma unroll
        for (int nf = 0; nf < 4; ++nf)
          *(short4v*)&VT[(nf * 16 + lo) * 36 + mf * 16 + hi * 4] = pk4(vacc[mf][nf]);

      /* S^T = K·Q^T: A=Kt rows=key, B=Q cols=q -> D col=q, row=key */
      f32x4 sacc[2][4];
#pragma unroll
      for (int mf = 0; mf < 2; ++mf)
#pragma unroll
        for (int nf = 0; nf < 4; ++nf) sacc[mf][nf] = (f32x4){0.f,0.f,0.f,0.f};
      short8 ka[2][2];
#pragma unroll
      for (int mf = 0; mf < 2; ++mf)
#pragma unroll
        for (int kf = 0; kf < 2; ++kf)
          ka[mf][kf] = ld8_lds(&QK[(mf * 16 + lo) * 68 + kf * 32 + hi * 8]);
#pragma unroll
      for (int mf = 0; mf < 2; ++mf)
#pragma unroll
        for (int nf = 0; nf < 4; ++nf)
#pragma unroll
          for (int kf = 0; kf < 2; ++kf)
            sacc[mf][nf] = __builtin_amdgcn_mfma_f32_16x16x32_bf16(ka[mf][kf], Qb[nf][kf], sacc[mf][nf], 0, 0, 0);

      /* online softmax per q (col=lo within nf; lanes hi=0..3 hold different keys) */
#pragma unroll
      for (int nf = 0; nf < 4; ++nf) {
        float cmax = sacc[0][nf][0];
#pragma unroll
        for (int r = 1; r < 4; ++r) cmax = fmaxf(cmax, sacc[0][nf][r]);
#pragma unroll
        for (int r = 0; r < 4; ++r) cmax = fmaxf(cmax, sacc[1][nf][r]);
        cmax = fmaxf(cmax, __shfl_xor(cmax, 16));
        cmax = fmaxf(cmax, __shfl_xor(cmax, 32));
        float mnew = fmaxf(mrow[nf], cmax);
        float corr = __expf(mrow[nf] - mnew);
        float ps = 0.f;
#pragma unroll
        for (int mf = 0; mf < 2; ++mf)
#pragma unroll
          for (int r = 0; r < 4; ++r) {
            float e = __expf(sacc[mf][nf][r] - mnew);
            sacc[mf][nf][r] = e; ps += e;
          }
        ps += __shfl_xor(ps, 16);
        ps += __shfl_xor(ps, 32);
        lrow[nf] = lrow[nf] * corr + ps;
        mrow[nf] = mnew;
#pragma unroll
        for (int mf = 0; mf < 4; ++mf) Ot[mf][nf] *= corr;
      }
      /* P[q][key] (b64-packed: rows=key consecutive) */
#pragma unroll
      for (int mf = 0; mf < 2; ++mf)
#pragma unroll
        for (int nf = 0; nf < 4; ++nf)
          *(short4v*)&P[(nf * 16 + lo) * 36 + mf * 16 + hi * 4] = pk4(sacc[mf][nf]);

      /* O^T += V^T·P^T: A=VT rows=d, B=P cols=q */
      short8 va[4], pb[4];
#pragma unroll
      for (int mf = 0; mf < 4; ++mf) va[mf] = ld8_lds(&VT[(mf * 16 + lo) * 36 + hi * 8]);
#pragma unroll
      for (int nf = 0; nf < 4; ++nf) pb[nf] = ld8_lds(&P[(nf * 16 + lo) * 36 + hi * 8]);
#pragma unroll
      for (int mf = 0; mf < 4; ++mf)
#pragma unroll
        for (int nf = 0; nf < 4; ++nf)
          Ot[mf][nf] = __builtin_amdgcn_mfma_f32_16x16x32_bf16(va[mf], pb[nf], Ot[mf][nf], 0, 0, 0);
    }

    /* finalize O, write Oall[tok][hd] (clobbers all scratch -> barrier first) */
    __syncthreads();
#pragma unroll
    for (int mf = 0; mf < 4; ++mf)
#pragma unroll
      for (int nf = 0; nf < 4; ++nf) {
        f32x4 o = Ot[mf][nf] * (1.f / lrow[nf]);
        *(short4v*)&Oall[(nf * 16 + lo) * 516 + h * 64 + mf * 16 + hi * 4] = pk4(o);
      }
    __syncthreads();

    /* out-proj: wave wv owns dims wv*16..wv*16+15; A=Oall rows=tok, B=Wout cols=dim */
    f32x4 pacc[4];
#pragma unroll
    for (int mf = 0; mf < 4; ++mf) pacc[mf] = (f32x4){0.f,0.f,0.f,0.f};
#pragma unroll
    for (int kf = 0; kf < 16; ++kf) {
      short8 bw = ld8_g(wout + (size_t)(wv * 16 + lo) * 512 + kf * 32 + hi * 8);
#pragma unroll
      for (int mf = 0; mf < 4; ++mf) {
        short8 aa = ld8_lds(&Oall[(mf * 16 + lo) * 516 + kf * 32 + hi * 8]);
        pacc[mf] = __builtin_amdgcn_mfma_f32_16x16x32_bf16(aa, bw, pacc[mf], 0, 0, 0);
      }
    }
#pragma unroll
    for (int mf = 0; mf < 4; ++mf)
#pragma unroll
      for (int r = 0; r < 4; ++r) {
        int tok = qbase + mf * 16 + hi * 4 + r;
        int i = tok >> 4, j = tok & 15;
        size_t addr = ((size_t)bidx * 65536 + (size_t)(sy + i) * HWD + (sx + j)) * DIM + wv * 16 + lo;
        atomicAdd(&out[addr], pacc[mf][r] + bias);
      }
  }
}

__global__ void k_final(const float* __restrict__ x, const float* __restrict__ cnt,
                        float* __restrict__ out) {
  size_t gid = (size_t)blockIdx.x * 256 + threadIdx.x;
  size_t pix = gid >> 7;
  float c = cnt[pix];
  out[gid] = x[gid] + out[gid] / (c + 1e-10f);
}

extern "C" void kernel_launch(void* const* d_in, const int* in_sizes, int n_in,
                              void* d_out, int out_size, void* d_ws, size_t ws_size,
                              hipStream_t stream) {
  const float* x    = (const float*)d_in[0];
  const float* prob = (const float*)d_in[1];
  const float* fixw = (const float*)d_in[2];
  const float* wqkv = (const float*)d_in[3];
  const float* wout = (const float*)d_in[4];
  const float* bout = (const float*)d_in[5];
  float* out = (float*)d_out;
  float* ws  = (float*)d_ws;
  if (ws_size < WS_FLOATS * sizeof(float)) return;  /* need ~15.2 MB scratch */

  float* ent  = ws + OFF_ENT;
  float* sc   = ws + OFF_SCORE;
  int*   keep = (int*)(ws + OFF_KEEP);
  float* cnt  = ws + OFF_CNT;
  unsigned short* wqkv_bf = (unsigned short*)(ws + OFF_WQKV);
  unsigned short* wout_bf = (unsigned short*)(ws + OFF_WOUT);
  unsigned short* tokbf   = (unsigned short*)(ws + OFF_TOKBF);

  hipMemsetAsync(out, 0, (size_t)out_size * sizeof(float), stream);
  hipMemsetAsync(cnt, 0, (size_t)NB * 65536 * sizeof(float), stream);
  k_entropy<<<256, 256, 0, stream>>>(prob, ent);
  k_score<<<(NB * NBOX + 255) / 256, 256, 0, stream>>>(ent, fixw, sc);
  k_wcvt<<<1024, 256, 0, stream>>>(wqkv, wout, wqkv_bf, wout_bf);
  k_nms<<<NB, 1024, 0, stream>>>(sc, keep);
  k_toks<<<NWTOT, 256, 0, stream>>>(x, keep, tokbf, cnt);
  k_attn<<<NWTOT, 512, 0, stream>>>(tokbf, wqkv_bf, wout_bf, bout, keep, out);
  k_final<<<(NB * 65536 * DIM) / 256, 256, 0, stream>>>(x, cnt, out);
}

// Round 4
// 681.043 us; speedup vs baseline: 6.9478x; 1.1777x over previous
//
#include <hip/hip_runtime.h>
#include <math.h>

#define NB 4
#define NWIN 121
#define NBOX (NWIN*NWIN)   /* 14641 */
#define NKEEP 50
#define HWD 256
#define DIM 128
#define HEADS 8
#define NTOK 256
#define NWTOT (NB*NKEEP)   /* 200 */

/* ws layout (float units) */
#define OFF_ENT   0          /* 65536 */
#define OFF_SCORE 65536      /* 58564 */
#define OFF_KEEP  124160     /* 400 ints = 100 floats */
#define OFF_CNT   131072     /* 262144 */
#define OFF_WQKV  393216     /* 196608 ushort = 98304 f */
#define OFF_WOUT  491520     /* 65536 ushort = 32768 f */
#define OFF_TOKBF 524288     /* 6553600 ushort = 3276800 f */
#define WS_FLOATS 3801088

typedef __attribute__((ext_vector_type(8))) short short8;
typedef __attribute__((ext_vector_type(4))) short short4v;
typedef __attribute__((ext_vector_type(4))) float f32x4;

static __device__ __forceinline__ unsigned short f2bf(float f) {
  union { float f; unsigned u; } v; v.f = f;
  unsigned r = (v.u + 0x7fffu + ((v.u >> 16) & 1u)) >> 16;
  return (unsigned short)r;
}
static __device__ __forceinline__ short4v pk4(f32x4 a) {
  short4v r;
  r[0] = (short)f2bf(a[0]); r[1] = (short)f2bf(a[1]);
  r[2] = (short)f2bf(a[2]); r[3] = (short)f2bf(a[3]);
  return r;
}
static __device__ __forceinline__ short8 ld8_lds(const unsigned short* p) {
  short4v a = *(const short4v*)p;
  short4v b = *(const short4v*)(p + 4);
  short8 r;
  r[0]=a[0]; r[1]=a[1]; r[2]=a[2]; r[3]=a[3];
  r[4]=b[0]; r[5]=b[1]; r[6]=b[2]; r[7]=b[3];
  return r;
}
static __device__ __forceinline__ short8 ld8_g(const unsigned short* p) {
  return *(const short8*)p;   /* 16B-aligned global */
}

__global__ void k_entropy(const float* __restrict__ prob, float* __restrict__ ent) {
  int idx = blockIdx.x * 256 + threadIdx.x;
  int b = idx >> 14, p = idx & 16383;
  float p0 = prob[(size_t)(b * 2) * 16384 + p];
  float p1 = prob[(size_t)(b * 2 + 1) * 16384 + p];
  ent[idx] = -(p0 * log2f(p0 + 1e-10f) + p1 * log2f(p1 + 1e-10f));
}

__global__ void k_score(const float* __restrict__ ent, const float* __restrict__ fw,
                        float* __restrict__ sc) {
  int gid = blockIdx.x * 256 + threadIdx.x;
  if (gid >= NB * NBOX) return;
  int b = gid / NBOX, rem = gid % NBOX;
  int oy = rem / NWIN, ox = rem % NWIN;
  const float* e = ent + b * 16384 + oy * 128 + ox;
  float s = 0.f;
#pragma unroll
  for (int r = 0; r < 8; ++r)
#pragma unroll
    for (int c = 0; c < 8; ++c)
      s += e[r * 128 + c] * fw[r * 8 + c];
  sc[gid] = s * (1.0f / 64.0f);
}

/* Single-wave NMS (64 threads/batch): the whole pick loop runs in one wave
   (lockstep + in-order same-wave LDS) -> no barriers, structurally
   deterministic. Row-max cache M/C; suppression radius 4 (inter>75 needs
   |d|<=4); repair only rows R-4..R+4. Tie-break = lowest flat index. */
__global__ void k_nms(const float* __restrict__ scores, int* __restrict__ keep) {
  __shared__ float sc[NWIN * 128];
  __shared__ float M[128];
  __shared__ int   C[128];
  int b = blockIdx.x, l = threadIdx.x;   /* 64 lanes */
  for (int idx = l; idx < NWIN * 128; idx += 64) {
    int r = idx >> 7, c = idx & 127;
    sc[idx] = (c < NWIN) ? scores[b * NBOX + r * NWIN + c] : -INFINITY;
  }
  /* row maxima: lane handles rows l and l+64; pad rows 121..127 = -INF */
#pragma unroll
  for (int base = 0; base < 128; base += 64) {
    int r = base + l;
    float bv = -INFINITY; int bc = 0;
    if (r < NWIN) {
      for (int c = 0; c < NWIN; ++c) {
        float v = sc[r * 128 + c];
        if (v > bv) { bv = v; bc = c; }   /* ascending c: lowest col wins ties */
      }
    }
    M[r] = bv; C[r] = bc;
  }
  for (int k = 0; k < NKEEP; ++k) {
    /* argmax over 128 row slots (pads are -INF, no guards) */
    float bv = M[l]; int br = l;
    float v2 = M[l + 64];
    if (v2 > bv) { bv = v2; br = l + 64; }
#pragma unroll
    for (int m = 32; m; m >>= 1) {
      float ov  = __shfl_xor(bv, m);
      int   orr = __shfl_xor(br, m);
      if (ov > bv || (ov == bv && orr < br)) { bv = ov; br = orr; }
    }
    int R = br;           /* wave-uniform */
    int Cc = C[R];        /* broadcast LDS read */
    if (l == 0) {
      keep[(b * NKEEP + k) * 2 + 0] = 2 * R;   /* sy */
      keep[(b * NKEEP + k) * 2 + 1] = 2 * Cc;  /* sx */
    }
    /* suppress + repair rows R-4..R+4: 8 lanes per row, 2 passes */
#pragma unroll
    for (int pass = 0; pass < 2; ++pass) {
      int pr = pass * 8 + (l >> 3);       /* patch row, uniform per 8-lane group */
      int rr = R - 4 + pr;
      if (pr < 9 && rr >= 0 && rr < NWIN) {
        int ady = pr < 4 ? 4 - pr : pr - 4;
        float ih = (float)(15 - 2 * ady);
        float nbv = -INFINITY; int nbc = 0;
        for (int c = l & 7; c < 128; c += 8) {
          float v = sc[rr * 128 + c];
          int adx = c > Cc ? c - Cc : Cc - c;
          if (adx <= 4) {
            float iw = (float)(15 - 2 * adx);
            float inter = iw * ih;
            float iou = inter / (450.0f - inter);
            if (!(iou <= 0.2f)) { v = -INFINITY; sc[rr * 128 + c] = v; }
          }
          if (v > nbv) { nbv = v; nbc = c; }
        }
#pragma unroll
        for (int m = 4; m; m >>= 1) {
          float ov = __shfl_xor(nbv, m);
          int   oc = __shfl_xor(nbc, m);
          if (ov > nbv || (ov == nbv && oc < nbc)) { nbv = ov; nbc = oc; }
        }
        if ((l & 7) == 0) { M[rr] = nbv; C[rr] = nbc; }
      }
    }
  }
}

__global__ void k_wcvt(const float* __restrict__ wqkv, const float* __restrict__ wout,
                       unsigned short* __restrict__ wqkv_bf, unsigned short* __restrict__ wout_bf) {
  int i = blockIdx.x * 256 + threadIdx.x;
  if (i < 196608) wqkv_bf[i] = f2bf(wqkv[i]);
  int j = i - 196608;
  if (j >= 0 && j < 65536) wout_bf[j] = f2bf(wout[j]);
}

__global__ void k_toks(const float* __restrict__ x, const int* __restrict__ keep,
                       unsigned short* __restrict__ tokbf, float* __restrict__ cnt) {
  int w = blockIdx.x;
  int b = w / NKEEP;
  int sy = keep[w * 2 + 0], sx = keep[w * 2 + 1];
  int tid = threadIdx.x;
  int ch = tid & 127, th = tid >> 7;
  const float* xb = x + (size_t)b * 65536 * DIM;
  for (int it = 0; it < 128; ++it) {
    int tk = it * 2 + th;
    int i = tk >> 4, j = tk & 15;
    float offy = (i + 0.5f) * 0.9375f;
    float offx = (j + 0.5f) * 0.9375f;
    int li = (int)offy, lj = (int)offx;
    float fy = offy - (float)li, fx = offx - (float)lj;
    const float* p = xb + ((size_t)((sy + li) * HWD + (sx + lj))) * DIM + ch;
    float v00 = p[0], v01 = p[DIM], v10 = p[HWD * DIM], v11 = p[HWD * DIM + DIM];
    float w00 = (1.f - fy) * (1.f - fx), w01 = (1.f - fy) * fx;
    float w10 = fy * (1.f - fx), w11 = fy * fx;
    tokbf[((size_t)w * NTOK + tk) * DIM + ch] = f2bf(w00 * v00 + w01 * v01 + w10 * v10 + w11 * v11);
    if (ch == 0) atomicAdd(&cnt[b * 65536 + (sy + i) * HWD + (sx + j)], 1.0f);
  }
}

/* LDS map (bytes):
   tok_lds  [256][132] bf16 : 0      .. 67584
   per-wave scratch (9216 B x 8 waves) at 67584:
     QK = Q[64][68] | Kt[32][68] | P[64][36]
     VT = [64][36]
   Oall [64][516] bf16 overlays the whole scratch region */
__global__ __launch_bounds__(512, 2) void k_attn(
    const unsigned short* __restrict__ tokbf,
    const unsigned short* __restrict__ wqkv,
    const unsigned short* __restrict__ wout,
    const float* __restrict__ bout,
    const int* __restrict__ keep,
    float* __restrict__ out) {
  __shared__ __align__(16) char smem[141312];
  unsigned short* tok_lds = (unsigned short*)smem;          /* [256][132] */
  char* scr = smem + 67584;
  const int tid = threadIdx.x;
  const int wv = tid >> 6, ln = tid & 63;
  const int lo = ln & 15, hi = ln >> 4;
  const int win = blockIdx.x;
  const int h = wv;
  unsigned short* QK = (unsigned short*)(scr + wv * 9216);
  unsigned short* VT = (unsigned short*)(scr + wv * 9216 + 4608);
  unsigned short* P  = QK;
  unsigned short* Oall = (unsigned short*)scr;              /* [64][516] */

  const unsigned short* tw = tokbf + (size_t)win * NTOK * DIM;
  for (int it = 0; it < 8; ++it) {
    int idx = it * 4096 + tid * 8;
    int r = idx >> 7, c = idx & 127;
    *(short4v*)&tok_lds[r * 132 + c]     = *(const short4v*)&tw[idx];
    *(short4v*)&tok_lds[r * 132 + c + 4] = *(const short4v*)&tw[idx + 4];
  }
  __syncthreads();

  const int sy = keep[win * 2 + 0], sx = keep[win * 2 + 1];
  const int bidx = win / NKEEP;
  const float bias = bout[wv * 16 + lo];

  for (int p = 0; p < 4; ++p) {
    if (p) __syncthreads();
    const int qbase = p * 64;

    /* Q-GEMM (transposed): A=Wq rows=d, B=toks cols=q */
    f32x4 qacc[4][4];
#pragma unroll
    for (int mf = 0; mf < 4; ++mf)
#pragma unroll
      for (int nf = 0; nf < 4; ++nf) qacc[mf][nf] = (f32x4){0.f,0.f,0.f,0.f};
#pragma unroll
    for (int kf = 0; kf < 4; ++kf) {
      short8 aw[4], bt[4];
#pragma unroll
      for (int mf = 0; mf < 4; ++mf)
        aw[mf] = ld8_g(wqkv + (size_t)(h * 64 + mf * 16 + lo) * 128 + kf * 32 + hi * 8);
#pragma unroll
      for (int nf = 0; nf < 4; ++nf)
        bt[nf] = ld8_lds(&tok_lds[(qbase + nf * 16 + lo) * 132 + kf * 32 + hi * 8]);
#pragma unroll
      for (int mf = 0; mf < 4; ++mf)
#pragma unroll
        for (int nf = 0; nf < 4; ++nf)
          qacc[mf][nf] = __builtin_amdgcn_mfma_f32_16x16x32_bf16(aw[mf], bt[nf], qacc[mf][nf], 0, 0, 0);
    }
#pragma unroll
    for (int mf = 0; mf < 4; ++mf)
#pragma unroll
      for (int nf = 0; nf < 4; ++nf) {
        f32x4 s = qacc[mf][nf] * 0.125f;
        *(short4v*)&QK[(nf * 16 + lo) * 68 + mf * 16 + hi * 4] = pk4(s);  /* Q[q][d] */
      }
    short8 Qb[4][2];
#pragma unroll
    for (int nf = 0; nf < 4; ++nf)
#pragma unroll
      for (int kf = 0; kf < 2; ++kf)
        Qb[nf][kf] = ld8_lds(&QK[(nf * 16 + lo) * 68 + kf * 32 + hi * 8]);

    f32x4 Ot[4][4];
#pragma unroll
    for (int mf = 0; mf < 4; ++mf)
#pragma unroll
      for (int nf = 0; nf < 4; ++nf) Ot[mf][nf] = (f32x4){0.f,0.f,0.f,0.f};
    float mrow[4] = {-INFINITY, -INFINITY, -INFINITY, -INFINITY};
    float lrow[4] = {0.f, 0.f, 0.f, 0.f};

    for (int ch = 0; ch < 8; ++ch) {
      const int kb = ch * 32;
      f32x4 kacc[4][2];
#pragma unroll
      for (int mf = 0; mf < 4; ++mf)
#pragma unroll
        for (int nf = 0; nf < 2; ++nf) kacc[mf][nf] = (f32x4){0.f,0.f,0.f,0.f};
#pragma unroll
      for (int kf = 0; kf < 4; ++kf) {
        short8 aw[4], bt[2];
#pragma unroll
        for (int mf = 0; mf < 4; ++mf)
          aw[mf] = ld8_g(wqkv + (size_t)(512 + h * 64 + mf * 16 + lo) * 128 + kf * 32 + hi * 8);
#pragma unroll
        for (int nf = 0; nf < 2; ++nf)
          bt[nf] = ld8_lds(&tok_lds[(kb + nf * 16 + lo) * 132 + kf * 32 + hi * 8]);
#pragma unroll
        for (int mf = 0; mf < 4; ++mf)
#pragma unroll
          for (int nf = 0; nf < 2; ++nf)
            kacc[mf][nf] = __builtin_amdgcn_mfma_f32_16x16x32_bf16(aw[mf], bt[nf], kacc[mf][nf], 0, 0, 0);
      }
#pragma unroll
      for (int mf = 0; mf < 4; ++mf)
#pragma unroll
        for (int nf = 0; nf < 2; ++nf)
          *(short4v*)&QK[(nf * 16 + lo) * 68 + mf * 16 + hi * 4] = pk4(kacc[mf][nf]);

      f32x4 vacc[2][4];
#pragma unroll
      for (int mf = 0; mf < 2; ++mf)
#pragma unroll
        for (int nf = 0; nf < 4; ++nf) vacc[mf][nf] = (f32x4){0.f,0.f,0.f,0.f};
#pragma unroll
      for (int kf = 0; kf < 4; ++kf) {
        short8 at[2], bw[4];
#pragma unroll
        for (int mf = 0; mf < 2; ++mf)
          at[mf] = ld8_lds(&tok_lds[(kb + mf * 16 + lo) * 132 + kf * 32 + hi * 8]);
#pragma unroll
        for (int nf = 0; nf < 4; ++nf)
          bw[nf] = ld8_g(wqkv + (size_t)(1024 + h * 64 + nf * 16 + lo) * 128 + kf * 32 + hi * 8);
#pragma unroll
        for (int mf = 0; mf < 2; ++mf)
#pragma unroll
          for (int nf = 0; nf < 4; ++nf)
            vacc[mf][nf] = __builtin_amdgcn_mfma_f32_16x16x32_bf16(at[mf], bw[nf], vacc[mf][nf], 0, 0, 0);
      }
#pragma unroll
      for (int mf = 0; mf < 2; ++mf)
#pragma unroll
        for (int nf = 0; nf < 4; ++nf)
          *(short4v*)&VT[(nf * 16 + lo) * 36 + mf * 16 + hi * 4] = pk4(vacc[mf][nf]);

      f32x4 sacc[2][4];
#pragma unroll
      for (int mf = 0; mf < 2; ++mf)
#pragma unroll
        for (int nf = 0; nf < 4; ++nf) sacc[mf][nf] = (f32x4){0.f,0.f,0.f,0.f};
      short8 ka[2][2];
#pragma unroll
      for (int mf = 0; mf < 2; ++mf)
#pragma unroll
        for (int kf = 0; kf < 2; ++kf)
          ka[mf][kf] = ld8_lds(&QK[(mf * 16 + lo) * 68 + kf * 32 + hi * 8]);
#pragma unroll
      for (int mf = 0; mf < 2; ++mf)
#pragma unroll
        for (int nf = 0; nf < 4; ++nf)
#pragma unroll
          for (int kf = 0; kf < 2; ++kf)
            sacc[mf][nf] = __builtin_amdgcn_mfma_f32_16x16x32_bf16(ka[mf][kf], Qb[nf][kf], sacc[mf][nf], 0, 0, 0);

#pragma unroll
      for (int nf = 0; nf < 4; ++nf) {
        float cmax = sacc[0][nf][0];
#pragma unroll
        for (int r = 1; r < 4; ++r) cmax = fmaxf(cmax, sacc[0][nf][r]);
#pragma unroll
        for (int r = 0; r < 4; ++r) cmax = fmaxf(cmax, sacc[1][nf][r]);
        cmax = fmaxf(cmax, __shfl_xor(cmax, 16));
        cmax = fmaxf(cmax, __shfl_xor(cmax, 32));
        float mnew = fmaxf(mrow[nf], cmax);
        float corr = __expf(mrow[nf] - mnew);
        float ps = 0.f;
#pragma unroll
        for (int mf = 0; mf < 2; ++mf)
#pragma unroll
          for (int r = 0; r < 4; ++r) {
            float e = __expf(sacc[mf][nf][r] - mnew);
            sacc[mf][nf][r] = e; ps += e;
          }
        ps += __shfl_xor(ps, 16);
        ps += __shfl_xor(ps, 32);
        lrow[nf] = lrow[nf] * corr + ps;
        mrow[nf] = mnew;
#pragma unroll
        for (int mf = 0; mf < 4; ++mf) Ot[mf][nf] *= corr;
      }
#pragma unroll
      for (int mf = 0; mf < 2; ++mf)
#pragma unroll
        for (int nf = 0; nf < 4; ++nf)
          *(short4v*)&P[(nf * 16 + lo) * 36 + mf * 16 + hi * 4] = pk4(sacc[mf][nf]);

      short8 va[4], pb[4];
#pragma unroll
      for (int mf = 0; mf < 4; ++mf) va[mf] = ld8_lds(&VT[(mf * 16 + lo) * 36 + hi * 8]);
#pragma unroll
      for (int nf = 0; nf < 4; ++nf) pb[nf] = ld8_lds(&P[(nf * 16 + lo) * 36 + hi * 8]);
#pragma unroll
      for (int mf = 0; mf < 4; ++mf)
#pragma unroll
        for (int nf = 0; nf < 4; ++nf)
          Ot[mf][nf] = __builtin_amdgcn_mfma_f32_16x16x32_bf16(va[mf], pb[nf], Ot[mf][nf], 0, 0, 0);
    }

    __syncthreads();
#pragma unroll
    for (int mf = 0; mf < 4; ++mf)
#pragma unroll
      for (int nf = 0; nf < 4; ++nf) {
        f32x4 o = Ot[mf][nf] * (1.f / lrow[nf]);
        *(short4v*)&Oall[(nf * 16 + lo) * 516 + h * 64 + mf * 16 + hi * 4] = pk4(o);
      }
    __syncthreads();

    f32x4 pacc[4];
#pragma unroll
    for (int mf = 0; mf < 4; ++mf) pacc[mf] = (f32x4){0.f,0.f,0.f,0.f};
#pragma unroll
    for (int kf = 0; kf < 16; ++kf) {
      short8 bw = ld8_g(wout + (size_t)(wv * 16 + lo) * 512 + kf * 32 + hi * 8);
#pragma unroll
      for (int mf = 0; mf < 4; ++mf) {
        short8 aa = ld8_lds(&Oall[(mf * 16 + lo) * 516 + kf * 32 + hi * 8]);
        pacc[mf] = __builtin_amdgcn_mfma_f32_16x16x32_bf16(aa, bw, pacc[mf], 0, 0, 0);
      }
    }
#pragma unroll
    for (int mf = 0; mf < 4; ++mf)
#pragma unroll
      for (int r = 0; r < 4; ++r) {
        int tok = qbase + mf * 16 + hi * 4 + r;
        int i = tok >> 4, j = tok & 15;
        size_t addr = ((size_t)bidx * 65536 + (size_t)(sy + i) * HWD + (sx + j)) * DIM + wv * 16 + lo;
        atomicAdd(&out[addr], pacc[mf][r] + bias);
      }
  }
}

__global__ void k_final(const float* __restrict__ x, const float* __restrict__ cnt,
                        float* __restrict__ out) {
  size_t gid = (size_t)blockIdx.x * 256 + threadIdx.x;
  size_t pix = gid >> 7;
  float c = cnt[pix];
  out[gid] = x[gid] + out[gid] / (c + 1e-10f);
}

extern "C" void kernel_launch(void* const* d_in, const int* in_sizes, int n_in,
                              void* d_out, int out_size, void* d_ws, size_t ws_size,
                              hipStream_t stream) {
  const float* x    = (const float*)d_in[0];
  const float* prob = (const float*)d_in[1];
  const float* fixw = (const float*)d_in[2];
  const float* wqkv = (const float*)d_in[3];
  const float* wout = (const float*)d_in[4];
  const float* bout = (const float*)d_in[5];
  float* out = (float*)d_out;
  float* ws  = (float*)d_ws;
  if (ws_size < WS_FLOATS * sizeof(float)) return;  /* need ~15.2 MB scratch */

  float* ent  = ws + OFF_ENT;
  float* sc   = ws + OFF_SCORE;
  int*   keep = (int*)(ws + OFF_KEEP);
  float* cnt  = ws + OFF_CNT;
  unsigned short* wqkv_bf = (unsigned short*)(ws + OFF_WQKV);
  unsigned short* wout_bf = (unsigned short*)(ws + OFF_WOUT);
  unsigned short* tokbf   = (unsigned short*)(ws + OFF_TOKBF);

  hipMemsetAsync(out, 0, (size_t)out_size * sizeof(float), stream);
  hipMemsetAsync(cnt, 0, (size_t)NB * 65536 * sizeof(float), stream);
  k_entropy<<<256, 256, 0, stream>>>(prob, ent);
  k_score<<<(NB * NBOX + 255) / 256, 256, 0, stream>>>(ent, fixw, sc);
  k_wcvt<<<1024, 256, 0, stream>>>(wqkv, wout, wqkv_bf, wout_bf);
  k_nms<<<NB, 64, 0, stream>>>(sc, keep);
  k_toks<<<NWTOT, 256, 0, stream>>>(x, keep, tokbf, cnt);
  k_attn<<<NWTOT, 512, 0, stream>>>(tokbf, wqkv_bf, wout_bf, bout, keep, out);
  k_final<<<(NB * 65536 * DIM) / 256, 256, 0, stream>>>(x, cnt, out);
}

// Round 5
// 541.667 us; speedup vs baseline: 8.7355x; 1.2573x over previous
//
#include <hip/hip_runtime.h>
#include <math.h>

#define NB 4
#define NWIN 121
#define NBOX (NWIN*NWIN)   /* 14641 */
#define NKEEP 50
#define HWD 256
#define DIM 128
#define HEADS 8
#define NTOK 256
#define NWTOT (NB*NKEEP)   /* 200 */

/* ws layout (float units) */
#define OFF_ENT   0          /* 65536 */
#define OFF_SCORE 65536      /* 58564 */
#define OFF_KEEP  124160     /* 400 B = 100 floats */
#define OFF_WQKV  124288     /* 196608 ushort = 98304 f */
#define OFF_WOUT  222592     /* 65536 ushort = 32768 f */
#define OFF_TOKBF 255360     /* 6553600 ushort = 3276800 f */
#define OFF_PO    3532160    /* 6553600 ushort = 3276800 f */
#define WS_FLOATS 6808960

#define KPAD 76
#define VPAD 268

typedef __attribute__((ext_vector_type(8))) short short8;
typedef __attribute__((ext_vector_type(4))) short short4v;
typedef __attribute__((ext_vector_type(4))) float f32x4;

static __device__ __forceinline__ unsigned short f2bf(float f) {
  union { float f; unsigned u; } v; v.f = f;
  unsigned r = (v.u + 0x7fffu + ((v.u >> 16) & 1u)) >> 16;
  return (unsigned short)r;
}
static __device__ __forceinline__ short4v pk4(f32x4 a) {
  short4v r;
  r[0] = (short)f2bf(a[0]); r[1] = (short)f2bf(a[1]);
  r[2] = (short)f2bf(a[2]); r[3] = (short)f2bf(a[3]);
  return r;
}
static __device__ __forceinline__ short8 ld8_lds(const unsigned short* p) {
  short4v a = *(const short4v*)p;
  short4v b = *(const short4v*)(p + 4);
  short8 r;
  r[0]=a[0]; r[1]=a[1]; r[2]=a[2]; r[3]=a[3];
  r[4]=b[0]; r[5]=b[1]; r[6]=b[2]; r[7]=b[3];
  return r;
}
static __device__ __forceinline__ short8 ld8_g(const unsigned short* p) {
  return *(const short8*)p;   /* 16B-aligned global */
}

__global__ void k_entropy(const float* __restrict__ prob, float* __restrict__ ent) {
  int idx = blockIdx.x * 256 + threadIdx.x;
  int b = idx >> 14, p = idx & 16383;
  float p0 = prob[(size_t)(b * 2) * 16384 + p];
  float p1 = prob[(size_t)(b * 2 + 1) * 16384 + p];
  ent[idx] = -(p0 * log2f(p0 + 1e-10f) + p1 * log2f(p1 + 1e-10f));
}

__global__ void k_score(const float* __restrict__ ent, const float* __restrict__ fw,
                        float* __restrict__ sc) {
  int gid = blockIdx.x * 256 + threadIdx.x;
  if (gid >= NB * NBOX) return;
  int b = gid / NBOX, rem = gid % NBOX;
  int oy = rem / NWIN, ox = rem % NWIN;
  const float* e = ent + b * 16384 + oy * 128 + ox;
  float s = 0.f;
#pragma unroll
  for (int r = 0; r < 8; ++r)
#pragma unroll
    for (int c = 0; c < 8; ++c)
      s += e[r * 128 + c] * fw[r * 8 + c];
  sc[gid] = s * (1.0f / 64.0f);
}

/* Single-wave NMS (proven R4): lockstep wave, no barriers, deterministic. */
__global__ void k_nms(const float* __restrict__ scores, int* __restrict__ keep) {
  __shared__ float sc[NWIN * 128];
  __shared__ float M[128];
  __shared__ int   C[128];
  int b = blockIdx.x, l = threadIdx.x;   /* 64 lanes */
  for (int idx = l; idx < NWIN * 128; idx += 64) {
    int r = idx >> 7, c = idx & 127;
    sc[idx] = (c < NWIN) ? scores[b * NBOX + r * NWIN + c] : -INFINITY;
  }
#pragma unroll
  for (int base = 0; base < 128; base += 64) {
    int r = base + l;
    float bv = -INFINITY; int bc = 0;
    if (r < NWIN) {
      for (int c = 0; c < NWIN; ++c) {
        float v = sc[r * 128 + c];
        if (v > bv) { bv = v; bc = c; }
      }
    }
    M[r] = bv; C[r] = bc;
  }
  for (int k = 0; k < NKEEP; ++k) {
    float bv = M[l]; int br = l;
    float v2 = M[l + 64];
    if (v2 > bv) { bv = v2; br = l + 64; }
#pragma unroll
    for (int m = 32; m; m >>= 1) {
      float ov  = __shfl_xor(bv, m);
      int   orr = __shfl_xor(br, m);
      if (ov > bv || (ov == bv && orr < br)) { bv = ov; br = orr; }
    }
    int R = br;
    int Cc = C[R];
    if (l == 0) {
      keep[(b * NKEEP + k) * 2 + 0] = 2 * R;
      keep[(b * NKEEP + k) * 2 + 1] = 2 * Cc;
    }
#pragma unroll
    for (int pass = 0; pass < 2; ++pass) {
      int pr = pass * 8 + (l >> 3);
      int rr = R - 4 + pr;
      if (pr < 9 && rr >= 0 && rr < NWIN) {
        int ady = pr < 4 ? 4 - pr : pr - 4;
        float ih = (float)(15 - 2 * ady);
        float nbv = -INFINITY; int nbc = 0;
        for (int c = l & 7; c < 128; c += 8) {
          float v = sc[rr * 128 + c];
          int adx = c > Cc ? c - Cc : Cc - c;
          if (adx <= 4) {
            float iw = (float)(15 - 2 * adx);
            float inter = iw * ih;
            float iou = inter / (450.0f - inter);
            if (!(iou <= 0.2f)) { v = -INFINITY; sc[rr * 128 + c] = v; }
          }
          if (v > nbv) { nbv = v; nbc = c; }
        }
#pragma unroll
        for (int m = 4; m; m >>= 1) {
          float ov = __shfl_xor(nbv, m);
          int   oc = __shfl_xor(nbc, m);
          if (ov > nbv || (ov == nbv && oc < nbc)) { nbv = ov; nbc = oc; }
        }
        if ((l & 7) == 0) { M[rr] = nbv; C[rr] = nbc; }
      }
    }
  }
}

__global__ void k_wcvt(const float* __restrict__ wqkv, const float* __restrict__ wout,
                       unsigned short* __restrict__ wqkv_bf, unsigned short* __restrict__ wout_bf) {
  int i = blockIdx.x * 256 + threadIdx.x;
  if (i < 196608) wqkv_bf[i] = f2bf(wqkv[i]);
  int j = i - 196608;
  if (j >= 0 && j < 65536) wout_bf[j] = f2bf(wout[j]);
}

__global__ void k_toks(const float* __restrict__ x, const int* __restrict__ keep,
                       unsigned short* __restrict__ tokbf) {
  int w = blockIdx.x;
  int b = w / NKEEP;
  int sy = keep[w * 2 + 0], sx = keep[w * 2 + 1];
  int tid = threadIdx.x;
  int ch = tid & 127, th = tid >> 7;
  const float* xb = x + (size_t)b * 65536 * DIM;
  for (int it = 0; it < 128; ++it) {
    int tk = it * 2 + th;
    int i = tk >> 4, j = tk & 15;
    float offy = (i + 0.5f) * 0.9375f;
    float offx = (j + 0.5f) * 0.9375f;
    int li = (int)offy, lj = (int)offx;
    float fy = offy - (float)li, fx = offx - (float)lj;
    const float* p = xb + ((size_t)((sy + li) * HWD + (sx + lj))) * DIM + ch;
    float v00 = p[0], v01 = p[DIM], v10 = p[HWD * DIM], v11 = p[HWD * DIM + DIM];
    float w00 = (1.f - fy) * (1.f - fx), w01 = (1.f - fy) * fx;
    float w10 = fy * (1.f - fx), w11 = fy * fx;
    tokbf[((size_t)w * NTOK + tk) * DIM + ch] = f2bf(w00 * v00 + w01 * v01 + w10 * v10 + w11 * v11);
  }
}

/* Per-window fused attention. 8 waves; head loop outer; per head:
   cooperative stage of K[256][76], VT[64][268], per-wave Q[32][76];
   flash over 4x64-key chunks; out-proj accumulated per head into pacc.
   LDS 112128 B. No atomics; result -> po[win][tok][dim] bf16. */
__global__ __launch_bounds__(512, 2) void k_attn(
    const unsigned short* __restrict__ tokbf,
    const unsigned short* __restrict__ wqkv,
    const unsigned short* __restrict__ wout,
    unsigned short* __restrict__ po) {
  __shared__ __align__(16) char smem[112128];
  unsigned short* Klds = (unsigned short*)smem;             /* [256][KPAD] */
  unsigned short* VT   = (unsigned short*)(smem + 38912);   /* [64][VPAD] */
  const int tid = threadIdx.x;
  const int wv = tid >> 6, ln = tid & 63;
  const int lo = ln & 15, hi = ln >> 4;
  const int win = blockIdx.x;
  unsigned short* QP = (unsigned short*)(smem + 73216 + wv * 4864);  /* [32][KPAD] */
  const unsigned short* tw = tokbf + (size_t)win * NTOK * DIM;
  const int qrow = wv * 32;

  f32x4 pacc[8][2];
#pragma unroll
  for (int mf = 0; mf < 8; ++mf)
#pragma unroll
    for (int nf = 0; nf < 2; ++nf) pacc[mf][nf] = (f32x4){0.f,0.f,0.f,0.f};

  for (int h = 0; h < HEADS; ++h) {
    if (h) __syncthreads();   /* protect Klds/VT rewrite vs prev-head readers */

    /* ---- K stage: Klds[key][d] for wave's 32 keys ---- */
    {
      f32x4 kacc[4][2];
#pragma unroll
      for (int mf = 0; mf < 4; ++mf)
#pragma unroll
        for (int nf = 0; nf < 2; ++nf) kacc[mf][nf] = (f32x4){0.f,0.f,0.f,0.f};
#pragma unroll
      for (int kf = 0; kf < 4; ++kf) {
        short8 aw[4], bt[2];
#pragma unroll
        for (int mf = 0; mf < 4; ++mf)
          aw[mf] = ld8_g(wqkv + (size_t)(512 + h * 64 + mf * 16 + lo) * 128 + kf * 32 + hi * 8);
#pragma unroll
        for (int nf = 0; nf < 2; ++nf)
          bt[nf] = ld8_g(&tw[(qrow + nf * 16 + lo) * 128 + kf * 32 + hi * 8]);
#pragma unroll
        for (int mf = 0; mf < 4; ++mf)
#pragma unroll
          for (int nf = 0; nf < 2; ++nf)
            kacc[mf][nf] = __builtin_amdgcn_mfma_f32_16x16x32_bf16(aw[mf], bt[nf], kacc[mf][nf], 0, 0, 0);
      }
#pragma unroll
      for (int mf = 0; mf < 4; ++mf)
#pragma unroll
        for (int nf = 0; nf < 2; ++nf)
          *(short4v*)&Klds[(qrow + nf * 16 + lo) * KPAD + mf * 16 + hi * 4] = pk4(kacc[mf][nf]);
    }
    /* ---- V stage: VT[d][key] for wave's 32 keys ---- */
    {
      f32x4 vacc[2][4];
#pragma unroll
      for (int mf = 0; mf < 2; ++mf)
#pragma unroll
        for (int nf = 0; nf < 4; ++nf) vacc[mf][nf] = (f32x4){0.f,0.f,0.f,0.f};
#pragma unroll
      for (int kf = 0; kf < 4; ++kf) {
        short8 at[2], bw[4];
#pragma unroll
        for (int mf = 0; mf < 2; ++mf)
          at[mf] = ld8_g(&tw[(qrow + mf * 16 + lo) * 128 + kf * 32 + hi * 8]);
#pragma unroll
        for (int nf = 0; nf < 4; ++nf)
          bw[nf] = ld8_g(wqkv + (size_t)(1024 + h * 64 + nf * 16 + lo) * 128 + kf * 32 + hi * 8);
#pragma unroll
        for (int mf = 0; mf < 2; ++mf)
#pragma unroll
          for (int nf = 0; nf < 4; ++nf)
            vacc[mf][nf] = __builtin_amdgcn_mfma_f32_16x16x32_bf16(at[mf], bw[nf], vacc[mf][nf], 0, 0, 0);
      }
#pragma unroll
      for (int mf = 0; mf < 2; ++mf)
#pragma unroll
        for (int nf = 0; nf < 4; ++nf)
          *(short4v*)&VT[(nf * 16 + lo) * VPAD + qrow + mf * 16 + hi * 4] = pk4(vacc[mf][nf]);
    }
    /* ---- Q stage: QP[q][d] for wave's 32 queries (scaled) ---- */
    {
      f32x4 qacc[4][2];
#pragma unroll
      for (int mf = 0; mf < 4; ++mf)
#pragma unroll
        for (int nf = 0; nf < 2; ++nf) qacc[mf][nf] = (f32x4){0.f,0.f,0.f,0.f};
#pragma unroll
      for (int kf = 0; kf < 4; ++kf) {
        short8 aw[4], bt[2];
#pragma unroll
        for (int mf = 0; mf < 4; ++mf)
          aw[mf] = ld8_g(wqkv + (size_t)(h * 64 + mf * 16 + lo) * 128 + kf * 32 + hi * 8);
#pragma unroll
        for (int nf = 0; nf < 2; ++nf)
          bt[nf] = ld8_g(&tw[(qrow + nf * 16 + lo) * 128 + kf * 32 + hi * 8]);
#pragma unroll
        for (int mf = 0; mf < 4; ++mf)
#pragma unroll
          for (int nf = 0; nf < 2; ++nf)
            qacc[mf][nf] = __builtin_amdgcn_mfma_f32_16x16x32_bf16(aw[mf], bt[nf], qacc[mf][nf], 0, 0, 0);
      }
#pragma unroll
      for (int mf = 0; mf < 4; ++mf)
#pragma unroll
        for (int nf = 0; nf < 2; ++nf)
          *(short4v*)&QP[(nf * 16 + lo) * KPAD + mf * 16 + hi * 4] = pk4(qacc[mf][nf] * 0.125f);
    }
    __syncthreads();   /* K/VT/Q visible to all waves */

    short8 Qb[2][2];
#pragma unroll
    for (int nf = 0; nf < 2; ++nf)
#pragma unroll
      for (int kf = 0; kf < 2; ++kf)
        Qb[nf][kf] = ld8_lds(&QP[(nf * 16 + lo) * KPAD + kf * 32 + hi * 8]);

    f32x4 Ot[4][2];
#pragma unroll
    for (int mf = 0; mf < 4; ++mf)
#pragma unroll
      for (int nf = 0; nf < 2; ++nf) Ot[mf][nf] = (f32x4){0.f,0.f,0.f,0.f};
    float mrow[2] = {-INFINITY, -INFINITY};
    float lrow[2] = {0.f, 0.f};

    for (int ck = 0; ck < 4; ++ck) {
      /* S^T = K·Q^T over 64-key chunk */
      f32x4 sacc[4][2];
#pragma unroll
      for (int mf = 0; mf < 4; ++mf)
#pragma unroll
        for (int nf = 0; nf < 2; ++nf) sacc[mf][nf] = (f32x4){0.f,0.f,0.f,0.f};
      short8 ka[4][2];
#pragma unroll
      for (int mf = 0; mf < 4; ++mf)
#pragma unroll
        for (int kf = 0; kf < 2; ++kf)
          ka[mf][kf] = ld8_lds(&Klds[(ck * 64 + mf * 16 + lo) * KPAD + kf * 32 + hi * 8]);
#pragma unroll
      for (int mf = 0; mf < 4; ++mf)
#pragma unroll
        for (int nf = 0; nf < 2; ++nf)
#pragma unroll
          for (int kf = 0; kf < 2; ++kf)
            sacc[mf][nf] = __builtin_amdgcn_mfma_f32_16x16x32_bf16(ka[mf][kf], Qb[nf][kf], sacc[mf][nf], 0, 0, 0);

      /* online softmax per q (lane lo = q within frag; hi spans keys) */
#pragma unroll
      for (int nf = 0; nf < 2; ++nf) {
        float cmax = -INFINITY;
#pragma unroll
        for (int mf = 0; mf < 4; ++mf)
#pragma unroll
          for (int r = 0; r < 4; ++r) cmax = fmaxf(cmax, sacc[mf][nf][r]);
        cmax = fmaxf(cmax, __shfl_xor(cmax, 16));
        cmax = fmaxf(cmax, __shfl_xor(cmax, 32));
        float mnew = fmaxf(mrow[nf], cmax);
        float corr = __expf(mrow[nf] - mnew);
        float ps = 0.f;
#pragma unroll
        for (int mf = 0; mf < 4; ++mf)
#pragma unroll
          for (int r = 0; r < 4; ++r) {
            float e = __expf(sacc[mf][nf][r] - mnew);
            sacc[mf][nf][r] = e; ps += e;
          }
        ps += __shfl_xor(ps, 16);
        ps += __shfl_xor(ps, 32);
        lrow[nf] = lrow[nf] * corr + ps;
        mrow[nf] = mnew;
#pragma unroll
        for (int mf = 0; mf < 4; ++mf) Ot[mf][nf] *= corr;
      }
      /* P -> QP (per-wave), then PV */
#pragma unroll
      for (int mf = 0; mf < 4; ++mf)
#pragma unroll
        for (int nf = 0; nf < 2; ++nf)
          *(short4v*)&QP[(nf * 16 + lo) * KPAD + mf * 16 + hi * 4] = pk4(sacc[mf][nf]);
      short8 pb[2][2], va[4][2];
#pragma unroll
      for (int nf = 0; nf < 2; ++nf)
#pragma unroll
        for (int kf = 0; kf < 2; ++kf)
          pb[nf][kf] = ld8_lds(&QP[(nf * 16 + lo) * KPAD + kf * 32 + hi * 8]);
#pragma unroll
      for (int mf = 0; mf < 4; ++mf)
#pragma unroll
        for (int kf = 0; kf < 2; ++kf)
          va[mf][kf] = ld8_lds(&VT[(mf * 16 + lo) * VPAD + ck * 64 + kf * 32 + hi * 8]);
#pragma unroll
      for (int mf = 0; mf < 4; ++mf)
#pragma unroll
        for (int nf = 0; nf < 2; ++nf)
#pragma unroll
          for (int kf = 0; kf < 2; ++kf)
            Ot[mf][nf] = __builtin_amdgcn_mfma_f32_16x16x32_bf16(va[mf][kf], pb[nf][kf], Ot[mf][nf], 0, 0, 0);
    }

    /* O finalize -> QP, out-proj partial accumulate */
#pragma unroll
    for (int nf = 0; nf < 2; ++nf) {
      float inv = 1.f / lrow[nf];
#pragma unroll
      for (int mf = 0; mf < 4; ++mf)
        *(short4v*)&QP[(nf * 16 + lo) * KPAD + mf * 16 + hi * 4] = pk4(Ot[mf][nf] * inv);
    }
    short8 Ob[2][2];
#pragma unroll
    for (int nf = 0; nf < 2; ++nf)
#pragma unroll
      for (int kf = 0; kf < 2; ++kf)
        Ob[nf][kf] = ld8_lds(&QP[(nf * 16 + lo) * KPAD + kf * 32 + hi * 8]);
#pragma unroll
    for (int kf = 0; kf < 2; ++kf) {
      short8 aw[8];
#pragma unroll
      for (int mf = 0; mf < 8; ++mf)
        aw[mf] = ld8_g(wout + (size_t)(mf * 16 + lo) * 512 + h * 64 + kf * 32 + hi * 8);
#pragma unroll
      for (int mf = 0; mf < 8; ++mf)
#pragma unroll
        for (int nf = 0; nf < 2; ++nf)
          pacc[mf][nf] = __builtin_amdgcn_mfma_f32_16x16x32_bf16(aw[mf], Ob[nf][kf], pacc[mf][nf], 0, 0, 0);
    }
  }

  /* po[win][tok][dim] bf16 */
#pragma unroll
  for (int mf = 0; mf < 8; ++mf)
#pragma unroll
    for (int nf = 0; nf < 2; ++nf)
      *(short4v*)&po[((size_t)win * NTOK + qrow + nf * 16 + lo) * 128 + mf * 16 + hi * 4] = pk4(pacc[mf][nf]);
}

/* Gather finalize: thread = (pixel, 32-ch quarter); loops 50 windows. */
__global__ void k_final(const float* __restrict__ x, const unsigned short* __restrict__ po,
                        const int* __restrict__ keep, const float* __restrict__ bout,
                        float* __restrict__ out) {
  __shared__ int kp[2 * NKEEP];
  int tid = threadIdx.x;
  int gid = blockIdx.x * 256 + tid;
  int chq = gid & 3, pix = gid >> 2;
  int b = pix >> 16, pb = pix & 65535, y = pb >> 8, xx = pb & 255;
  if (tid < 2 * NKEEP) kp[tid] = keep[b * 2 * NKEEP + tid];
  __syncthreads();
  float acc[32];
#pragma unroll
  for (int i = 0; i < 32; ++i) acc[i] = 0.f;
  float cnt = 0.f;
  for (int w = 0; w < NKEEP; ++w) {
    int dy = y - kp[2 * w], dx = xx - kp[2 * w + 1];
    if ((unsigned)dy < 16u && (unsigned)dx < 16u) {
      cnt += 1.f;
      const unsigned short* pp = po + ((size_t)(b * NKEEP + w) * NTOK + dy * 16 + dx) * 128 + chq * 32;
#pragma unroll
      for (int k2 = 0; k2 < 4; ++k2) {
        short8 v = ld8_g(pp + k2 * 8);
#pragma unroll
        for (int j = 0; j < 8; ++j) {
          union { unsigned u; float f; } cv;
          cv.u = ((unsigned)(unsigned short)v[j]) << 16;
          acc[k2 * 8 + j] += cv.f;
        }
      }
    }
  }
  size_t base = (size_t)pix * 128 + chq * 32;
  float inv = 1.f / (cnt + 1e-10f);
#pragma unroll
  for (int i = 0; i < 32; ++i)
    out[base + i] = x[base + i] + (acc[i] + cnt * bout[chq * 32 + i]) * inv;
}

extern "C" void kernel_launch(void* const* d_in, const int* in_sizes, int n_in,
                              void* d_out, int out_size, void* d_ws, size_t ws_size,
                              hipStream_t stream) {
  const float* x    = (const float*)d_in[0];
  const float* prob = (const float*)d_in[1];
  const float* fixw = (const float*)d_in[2];
  const float* wqkv = (const float*)d_in[3];
  const float* wout = (const float*)d_in[4];
  const float* bout = (const float*)d_in[5];
  float* out = (float*)d_out;
  float* ws  = (float*)d_ws;
  if (ws_size < WS_FLOATS * sizeof(float)) return;  /* need ~27.2 MB scratch */

  float* ent  = ws + OFF_ENT;
  float* sc   = ws + OFF_SCORE;
  int*   keep = (int*)(ws + OFF_KEEP);
  unsigned short* wqkv_bf = (unsigned short*)(ws + OFF_WQKV);
  unsigned short* wout_bf = (unsigned short*)(ws + OFF_WOUT);
  unsigned short* tokbf   = (unsigned short*)(ws + OFF_TOKBF);
  unsigned short* po      = (unsigned short*)(ws + OFF_PO);

  k_entropy<<<256, 256, 0, stream>>>(prob, ent);
  k_score<<<(NB * NBOX + 255) / 256, 256, 0, stream>>>(ent, fixw, sc);
  k_wcvt<<<1024, 256, 0, stream>>>(wqkv, wout, wqkv_bf, wout_bf);
  k_nms<<<NB, 64, 0, stream>>>(sc, keep);
  k_toks<<<NWTOT, 256, 0, stream>>>(x, keep, tokbf);
  k_attn<<<NWTOT, 512, 0, stream>>>(tokbf, wqkv_bf, wout_bf, po);
  k_final<<<NB * 65536 * 4 / 256, 256, 0, stream>>>(x, po, keep, bout, out);
}

// Round 6
// 517.680 us; speedup vs baseline: 9.1403x; 1.0463x over previous
//
#include <hip/hip_runtime.h>
#include <math.h>

#define NB 4
#define NWIN 121
#define NBOX (NWIN*NWIN)   /* 14641 */
#define NKEEP 50
#define HWD 256
#define DIM 128
#define HEADS 8
#define NTOK 256
#define NWTOT (NB*NKEEP)   /* 200 */

/* ws layout (float units) */
#define OFF_ENT   0          /* 65536 */
#define OFF_SCORE 65536      /* 58564 */
#define OFF_KEEP  124160     /* 400 B = 100 floats */
#define OFF_WQKV  124288     /* 196608 ushort = 98304 f */
#define OFF_WOUT  222592     /* 65536 ushort = 32768 f */
#define OFF_TOKBF 255360     /* 6553600 ushort = 3276800 f */
#define OFF_PO    3532160    /* 6553600 ushort = 3276800 f */
#define WS_FLOATS 6808960

#define KPAD 76
#define VPAD 268

typedef __attribute__((ext_vector_type(8))) short short8;
typedef __attribute__((ext_vector_type(4))) short short4v;
typedef __attribute__((ext_vector_type(4))) float f32x4;

static __device__ __forceinline__ unsigned short f2bf(float f) {
  union { float f; unsigned u; } v; v.f = f;
  unsigned r = (v.u + 0x7fffu + ((v.u >> 16) & 1u)) >> 16;
  return (unsigned short)r;
}
static __device__ __forceinline__ short4v pk4(f32x4 a) {
  short4v r;
  r[0] = (short)f2bf(a[0]); r[1] = (short)f2bf(a[1]);
  r[2] = (short)f2bf(a[2]); r[3] = (short)f2bf(a[3]);
  return r;
}
static __device__ __forceinline__ short8 ld8_lds(const unsigned short* p) {
  short4v a = *(const short4v*)p;
  short4v b = *(const short4v*)(p + 4);
  short8 r;
  r[0]=a[0]; r[1]=a[1]; r[2]=a[2]; r[3]=a[3];
  r[4]=b[0]; r[5]=b[1]; r[6]=b[2]; r[7]=b[3];
  return r;
}
static __device__ __forceinline__ short8 ld8_g(const unsigned short* p) {
  return *(const short8*)p;   /* 16B-aligned global */
}

__global__ void k_entropy(const float* __restrict__ prob, float* __restrict__ ent) {
  int idx = blockIdx.x * 256 + threadIdx.x;
  int b = idx >> 14, p = idx & 16383;
  float p0 = prob[(size_t)(b * 2) * 16384 + p];
  float p1 = prob[(size_t)(b * 2 + 1) * 16384 + p];
  ent[idx] = -(p0 * log2f(p0 + 1e-10f) + p1 * log2f(p1 + 1e-10f));
}

__global__ void k_score(const float* __restrict__ ent, const float* __restrict__ fw,
                        float* __restrict__ sc) {
  int gid = blockIdx.x * 256 + threadIdx.x;
  if (gid >= NB * NBOX) return;
  int b = gid / NBOX, rem = gid % NBOX;
  int oy = rem / NWIN, ox = rem % NWIN;
  const float* e = ent + b * 16384 + oy * 128 + ox;
  float s = 0.f;
#pragma unroll
  for (int r = 0; r < 8; ++r)
#pragma unroll
    for (int c = 0; c < 8; ++c)
      s += e[r * 128 + c] * fw[r * 8 + c];
  sc[gid] = s * (1.0f / 64.0f);
}

/* Single-wave NMS, register-resident row-max cache.
   Lane l owns rows l (slot0) and l+64 (slot1). Per pick:
   - argmax: 6-step shfl butterfly over register M (no LDS)
   - suppression: <=81 cells (9x9 minus 3 corner pairs; integer inter>75
     is bit-equivalent to the fp32 IoU test), 2 masked LDS writes
   - repair: ballot of rows whose cached argmax cell was suppressed
     (typically 1-3), whole-wave rescan of only those rows.
   Lockstep wave, uniform branches, in-order same-wave LDS -> deterministic. */
__global__ void k_nms(const float* __restrict__ scores, int* __restrict__ keep) {
  __shared__ float sc[NWIN * 128];
  int b = blockIdx.x, l = threadIdx.x;   /* 64 lanes */
  for (int idx = l; idx < NWIN * 128; idx += 64) {
    int r = idx >> 7, c = idx & 127;
    sc[idx] = (c < NWIN) ? scores[b * NBOX + r * NWIN + c] : -INFINITY;
  }
  /* row maxima -> registers */
  float M0 = -INFINITY, M1 = -INFINITY; int C0 = 0, C1 = 0;
  {
    int r = l;                           /* rows 0..63 */
    for (int c = 0; c < NWIN; ++c) {
      float v = sc[r * 128 + c];
      if (v > M0) { M0 = v; C0 = c; }    /* ascending c: lowest col wins ties */
    }
  }
  if (l + 64 < NWIN) {                   /* rows 64..120 */
    int r = l + 64;
    for (int c = 0; c < NWIN; ++c) {
      float v = sc[r * 128 + c];
      if (v > M1) { M1 = v; C1 = c; }
    }
  }
  for (int k = 0; k < NKEEP; ++k) {
    /* argmax over 128 row slots (slot1 of lanes 57..63 is -INF) */
    float bv = M0; int br = l;
    if (M1 > bv) { bv = M1; br = l + 64; }   /* strict >: lower row wins ties */
#pragma unroll
    for (int m = 32; m; m >>= 1) {
      float ov  = __shfl_xor(bv, m);
      int   orr = __shfl_xor(br, m);
      if (ov > bv || (ov == bv && orr < br)) { bv = ov; br = orr; }
    }
    int R = br;                               /* wave-uniform */
    int c0r = __shfl(C0, R & 63);
    int c1r = __shfl(C1, R & 63);
    int Cc = (R >= 64) ? c1r : c0r;
    if (l == 0) {
      keep[(b * NKEEP + k) * 2 + 0] = 2 * R;   /* sy */
      keep[(b * NKEEP + k) * 2 + 1] = 2 * Cc;  /* sx */
    }
    /* suppression: cells e = l and l+64 of the 9x9 patch */
#pragma unroll
    for (int pass = 0; pass < 2; ++pass) {
      int e = pass * 64 + l;
      if (e < 81) {
        int dy = e / 9 - 4, dx = e % 9 - 4;
        int rr = R + dy, cc = Cc + dx;
        int ady = dy < 0 ? -dy : dy, adx = dx < 0 ? -dx : dx;
        int inter = (15 - 2 * adx) * (15 - 2 * ady);
        if (inter > 75 && rr >= 0 && rr < NWIN && cc >= 0 && cc < NWIN)
          sc[rr * 128 + cc] = -INFINITY;
      }
    }
    /* which cached rows lost their argmax cell? */
    bool n0 = false, n1 = false;
    {
      int ady = l > R ? l - R : R - l;
      if (ady <= 4) {
        int adx = C0 > Cc ? C0 - Cc : Cc - C0;
        if (adx <= 4) n0 = (15 - 2 * adx) * (15 - 2 * ady) > 75;
      }
    }
    if (l + 64 < NWIN) {
      int r1 = l + 64;
      int ady = r1 > R ? r1 - R : R - r1;
      if (ady <= 4) {
        int adx = C1 > Cc ? C1 - Cc : Cc - C1;
        if (adx <= 4) n1 = (15 - 2 * adx) * (15 - 2 * ady) > 75;
      }
    }
    unsigned long long need0 = __ballot(n0);
    unsigned long long need1 = __ballot(n1);
    while (need0 | need1) {
      int rr;
      if (need0) { rr = __ffsll((long long)need0) - 1; need0 &= need0 - 1; }
      else       { rr = __ffsll((long long)need1) - 1 + 64; need1 &= need1 - 1; }
      float v0 = sc[rr * 128 + l];
      float v1 = sc[rr * 128 + 64 + l];       /* cols >=121 are -INF pad */
      float bv2; int bc2;
      if (v1 > v0) { bv2 = v1; bc2 = l + 64; } else { bv2 = v0; bc2 = l; }
#pragma unroll
      for (int m = 32; m; m >>= 1) {
        float ov = __shfl_xor(bv2, m);
        int   oc = __shfl_xor(bc2, m);
        if (ov > bv2 || (ov == bv2 && oc < bc2)) { bv2 = ov; bc2 = oc; }
      }
      if (l == (rr & 63)) {
        if (rr >= 64) { M1 = bv2; C1 = bc2; }
        else          { M0 = bv2; C0 = bc2; }
      }
    }
  }
}

__global__ void k_wcvt(const float* __restrict__ wqkv, const float* __restrict__ wout,
                       unsigned short* __restrict__ wqkv_bf, unsigned short* __restrict__ wout_bf) {
  int i = blockIdx.x * 256 + threadIdx.x;
  if (i < 196608) wqkv_bf[i] = f2bf(wqkv[i]);
  int j = i - 196608;
  if (j >= 0 && j < 65536) wout_bf[j] = f2bf(wout[j]);
}

__global__ void k_toks(const float* __restrict__ x, const int* __restrict__ keep,
                       unsigned short* __restrict__ tokbf) {
  int w = blockIdx.x;
  int b = w / NKEEP;
  int sy = keep[w * 2 + 0], sx = keep[w * 2 + 1];
  int tid = threadIdx.x;
  int ch = tid & 127, th = tid >> 7;
  const float* xb = x + (size_t)b * 65536 * DIM;
  for (int it = 0; it < 128; ++it) {
    int tk = it * 2 + th;
    int i = tk >> 4, j = tk & 15;
    float offy = (i + 0.5f) * 0.9375f;
    float offx = (j + 0.5f) * 0.9375f;
    int li = (int)offy, lj = (int)offx;
    float fy = offy - (float)li, fx = offx - (float)lj;
    const float* p = xb + ((size_t)((sy + li) * HWD + (sx + lj))) * DIM + ch;
    float v00 = p[0], v01 = p[DIM], v10 = p[HWD * DIM], v11 = p[HWD * DIM + DIM];
    float w00 = (1.f - fy) * (1.f - fx), w01 = (1.f - fy) * fx;
    float w10 = fy * (1.f - fx), w11 = fy * fx;
    tokbf[((size_t)w * NTOK + tk) * DIM + ch] = f2bf(w00 * v00 + w01 * v01 + w10 * v10 + w11 * v11);
  }
}

/* Per-window fused attention (proven R5). 8 waves; head loop outer. */
__global__ __launch_bounds__(512, 2) void k_attn(
    const unsigned short* __restrict__ tokbf,
    const unsigned short* __restrict__ wqkv,
    const unsigned short* __restrict__ wout,
    unsigned short* __restrict__ po) {
  __shared__ __align__(16) char smem[112128];
  unsigned short* Klds = (unsigned short*)smem;             /* [256][KPAD] */
  unsigned short* VT   = (unsigned short*)(smem + 38912);   /* [64][VPAD] */
  const int tid = threadIdx.x;
  const int wv = tid >> 6, ln = tid & 63;
  const int lo = ln & 15, hi = ln >> 4;
  const int win = blockIdx.x;
  unsigned short* QP = (unsigned short*)(smem + 73216 + wv * 4864);  /* [32][KPAD] */
  const unsigned short* tw = tokbf + (size_t)win * NTOK * DIM;
  const int qrow = wv * 32;

  f32x4 pacc[8][2];
#pragma unroll
  for (int mf = 0; mf < 8; ++mf)
#pragma unroll
    for (int nf = 0; nf < 2; ++nf) pacc[mf][nf] = (f32x4){0.f,0.f,0.f,0.f};

  for (int h = 0; h < HEADS; ++h) {
    if (h) __syncthreads();

    /* K stage */
    {
      f32x4 kacc[4][2];
#pragma unroll
      for (int mf = 0; mf < 4; ++mf)
#pragma unroll
        for (int nf = 0; nf < 2; ++nf) kacc[mf][nf] = (f32x4){0.f,0.f,0.f,0.f};
#pragma unroll
      for (int kf = 0; kf < 4; ++kf) {
        short8 aw[4], bt[2];
#pragma unroll
        for (int mf = 0; mf < 4; ++mf)
          aw[mf] = ld8_g(wqkv + (size_t)(512 + h * 64 + mf * 16 + lo) * 128 + kf * 32 + hi * 8);
#pragma unroll
        for (int nf = 0; nf < 2; ++nf)
          bt[nf] = ld8_g(&tw[(qrow + nf * 16 + lo) * 128 + kf * 32 + hi * 8]);
#pragma unroll
        for (int mf = 0; mf < 4; ++mf)
#pragma unroll
          for (int nf = 0; nf < 2; ++nf)
            kacc[mf][nf] = __builtin_amdgcn_mfma_f32_16x16x32_bf16(aw[mf], bt[nf], kacc[mf][nf], 0, 0, 0);
      }
#pragma unroll
      for (int mf = 0; mf < 4; ++mf)
#pragma unroll
        for (int nf = 0; nf < 2; ++nf)
          *(short4v*)&Klds[(qrow + nf * 16 + lo) * KPAD + mf * 16 + hi * 4] = pk4(kacc[mf][nf]);
    }
    /* V stage */
    {
      f32x4 vacc[2][4];
#pragma unroll
      for (int mf = 0; mf < 2; ++mf)
#pragma unroll
        for (int nf = 0; nf < 4; ++nf) vacc[mf][nf] = (f32x4){0.f,0.f,0.f,0.f};
#pragma unroll
      for (int kf = 0; kf < 4; ++kf) {
        short8 at[2], bw[4];
#pragma unroll
        for (int mf = 0; mf < 2; ++mf)
          at[mf] = ld8_g(&tw[(qrow + mf * 16 + lo) * 128 + kf * 32 + hi * 8]);
#pragma unroll
        for (int nf = 0; nf < 4; ++nf)
          bw[nf] = ld8_g(wqkv + (size_t)(1024 + h * 64 + nf * 16 + lo) * 128 + kf * 32 + hi * 8);
#pragma unroll
        for (int mf = 0; mf < 2; ++mf)
#pragma unroll
          for (int nf = 0; nf < 4; ++nf)
            vacc[mf][nf] = __builtin_amdgcn_mfma_f32_16x16x32_bf16(at[mf], bw[nf], vacc[mf][nf], 0, 0, 0);
      }
#pragma unroll
      for (int mf = 0; mf < 2; ++mf)
#pragma unroll
        for (int nf = 0; nf < 4; ++nf)
          *(short4v*)&VT[(nf * 16 + lo) * VPAD + qrow + mf * 16 + hi * 4] = pk4(vacc[mf][nf]);
    }
    /* Q stage */
    {
      f32x4 qacc[4][2];
#pragma unroll
      for (int mf = 0; mf < 4; ++mf)
#pragma unroll
        for (int nf = 0; nf < 2; ++nf) qacc[mf][nf] = (f32x4){0.f,0.f,0.f,0.f};
#pragma unroll
      for (int kf = 0; kf < 4; ++kf) {
        short8 aw[4], bt[2];
#pragma unroll
        for (int mf = 0; mf < 4; ++mf)
          aw[mf] = ld8_g(wqkv + (size_t)(h * 64 + mf * 16 + lo) * 128 + kf * 32 + hi * 8);
#pragma unroll
        for (int nf = 0; nf < 2; ++nf)
          bt[nf] = ld8_g(&tw[(qrow + nf * 16 + lo) * 128 + kf * 32 + hi * 8]);
#pragma unroll
        for (int mf = 0; mf < 4; ++mf)
#pragma unroll
          for (int nf = 0; nf < 2; ++nf)
            qacc[mf][nf] = __builtin_amdgcn_mfma_f32_16x16x32_bf16(aw[mf], bt[nf], qacc[mf][nf], 0, 0, 0);
      }
#pragma unroll
      for (int mf = 0; mf < 4; ++mf)
#pragma unroll
        for (int nf = 0; nf < 2; ++nf)
          *(short4v*)&QP[(nf * 16 + lo) * KPAD + mf * 16 + hi * 4] = pk4(qacc[mf][nf] * 0.125f);
    }
    __syncthreads();

    short8 Qb[2][2];
#pragma unroll
    for (int nf = 0; nf < 2; ++nf)
#pragma unroll
      for (int kf = 0; kf < 2; ++kf)
        Qb[nf][kf] = ld8_lds(&QP[(nf * 16 + lo) * KPAD + kf * 32 + hi * 8]);

    f32x4 Ot[4][2];
#pragma unroll
    for (int mf = 0; mf < 4; ++mf)
#pragma unroll
      for (int nf = 0; nf < 2; ++nf) Ot[mf][nf] = (f32x4){0.f,0.f,0.f,0.f};
    float mrow[2] = {-INFINITY, -INFINITY};
    float lrow[2] = {0.f, 0.f};

    for (int ck = 0; ck < 4; ++ck) {
      f32x4 sacc[4][2];
#pragma unroll
      for (int mf = 0; mf < 4; ++mf)
#pragma unroll
        for (int nf = 0; nf < 2; ++nf) sacc[mf][nf] = (f32x4){0.f,0.f,0.f,0.f};
      short8 ka[4][2];
#pragma unroll
      for (int mf = 0; mf < 4; ++mf)
#pragma unroll
        for (int kf = 0; kf < 2; ++kf)
          ka[mf][kf] = ld8_lds(&Klds[(ck * 64 + mf * 16 + lo) * KPAD + kf * 32 + hi * 8]);
#pragma unroll
      for (int mf = 0; mf < 4; ++mf)
#pragma unroll
        for (int nf = 0; nf < 2; ++nf)
#pragma unroll
          for (int kf = 0; kf < 2; ++kf)
            sacc[mf][nf] = __builtin_amdgcn_mfma_f32_16x16x32_bf16(ka[mf][kf], Qb[nf][kf], sacc[mf][nf], 0, 0, 0);

#pragma unroll
      for (int nf = 0; nf < 2; ++nf) {
        float cmax = -INFINITY;
#pragma unroll
        for (int mf = 0; mf < 4; ++mf)
#pragma unroll
          for (int r = 0; r < 4; ++r) cmax = fmaxf(cmax, sacc[mf][nf][r]);
        cmax = fmaxf(cmax, __shfl_xor(cmax, 16));
        cmax = fmaxf(cmax, __shfl_xor(cmax, 32));
        float mnew = fmaxf(mrow[nf], cmax);
        float corr = __expf(mrow[nf] - mnew);
        float ps = 0.f;
#pragma unroll
        for (int mf = 0; mf < 4; ++mf)
#pragma unroll
          for (int r = 0; r < 4; ++r) {
            float e = __expf(sacc[mf][nf][r] - mnew);
            sacc[mf][nf][r] = e; ps += e;
          }
        ps += __shfl_xor(ps, 16);
        ps += __shfl_xor(ps, 32);
        lrow[nf] = lrow[nf] * corr + ps;
        mrow[nf] = mnew;
#pragma unroll
        for (int mf = 0; mf < 4; ++mf) Ot[mf][nf] *= corr;
      }
#pragma unroll
      for (int mf = 0; mf < 4; ++mf)
#pragma unroll
        for (int nf = 0; nf < 2; ++nf)
          *(short4v*)&QP[(nf * 16 + lo) * KPAD + mf * 16 + hi * 4] = pk4(sacc[mf][nf]);
      short8 pb[2][2], va[4][2];
#pragma unroll
      for (int nf = 0; nf < 2; ++nf)
#pragma unroll
        for (int kf = 0; kf < 2; ++kf)
          pb[nf][kf] = ld8_lds(&QP[(nf * 16 + lo) * KPAD + kf * 32 + hi * 8]);
#pragma unroll
      for (int mf = 0; mf < 4; ++mf)
#pragma unroll
        for (int kf = 0; kf < 2; ++kf)
          va[mf][kf] = ld8_lds(&VT[(mf * 16 + lo) * VPAD + ck * 64 + kf * 32 + hi * 8]);
#pragma unroll
      for (int mf = 0; mf < 4; ++mf)
#pragma unroll
        for (int nf = 0; nf < 2; ++nf)
#pragma unroll
          for (int kf = 0; kf < 2; ++kf)
            Ot[mf][nf] = __builtin_amdgcn_mfma_f32_16x16x32_bf16(va[mf][kf], pb[nf][kf], Ot[mf][nf], 0, 0, 0);
    }

#pragma unroll
    for (int nf = 0; nf < 2; ++nf) {
      float inv = 1.f / lrow[nf];
#pragma unroll
      for (int mf = 0; mf < 4; ++mf)
        *(short4v*)&QP[(nf * 16 + lo) * KPAD + mf * 16 + hi * 4] = pk4(Ot[mf][nf] * inv);
    }
    short8 Ob[2][2];
#pragma unroll
    for (int nf = 0; nf < 2; ++nf)
#pragma unroll
      for (int kf = 0; kf < 2; ++kf)
        Ob[nf][kf] = ld8_lds(&QP[(nf * 16 + lo) * KPAD + kf * 32 + hi * 8]);
#pragma unroll
    for (int kf = 0; kf < 2; ++kf) {
      short8 aw[8];
#pragma unroll
      for (int mf = 0; mf < 8; ++mf)
        aw[mf] = ld8_g(wout + (size_t)(mf * 16 + lo) * 512 + h * 64 + kf * 32 + hi * 8);
#pragma unroll
      for (int mf = 0; mf < 8; ++mf)
#pragma unroll
        for (int nf = 0; nf < 2; ++nf)
          pacc[mf][nf] = __builtin_amdgcn_mfma_f32_16x16x32_bf16(aw[mf], Ob[nf][kf], pacc[mf][nf], 0, 0, 0);
    }
  }

#pragma unroll
  for (int mf = 0; mf < 8; ++mf)
#pragma unroll
    for (int nf = 0; nf < 2; ++nf)
      *(short4v*)&po[((size_t)win * NTOK + qrow + nf * 16 + lo) * 128 + mf * 16 + hi * 4] = pk4(pacc[mf][nf]);
}

/* Gather finalize: thread = (pixel, 32-ch quarter); loops 50 windows. */
__global__ void k_final(const float* __restrict__ x, const unsigned short* __restrict__ po,
                        const int* __restrict__ keep, const float* __restrict__ bout,
                        float* __restrict__ out) {
  __shared__ int kp[2 * NKEEP];
  int tid = threadIdx.x;
  int gid = blockIdx.x * 256 + tid;
  int chq = gid & 3, pix = gid >> 2;
  int b = pix >> 16, pb = pix & 65535, y = pb >> 8, xx = pb & 255;
  if (tid < 2 * NKEEP) kp[tid] = keep[b * 2 * NKEEP + tid];
  __syncthreads();
  float acc[32];
#pragma unroll
  for (int i = 0; i < 32; ++i) acc[i] = 0.f;
  float cnt = 0.f;
  for (int w = 0; w < NKEEP; ++w) {
    int dy = y - kp[2 * w], dx = xx - kp[2 * w + 1];
    if ((unsigned)dy < 16u && (unsigned)dx < 16u) {
      cnt += 1.f;
      const unsigned short* pp = po + ((size_t)(b * NKEEP + w) * NTOK + dy * 16 + dx) * 128 + chq * 32;
#pragma unroll
      for (int k2 = 0; k2 < 4; ++k2) {
        short8 v = ld8_g(pp + k2 * 8);
#pragma unroll
        for (int j = 0; j < 8; ++j) {
          union { unsigned u; float f; } cv;
          cv.u = ((unsigned)(unsigned short)v[j]) << 16;
          acc[k2 * 8 + j] += cv.f;
        }
      }
    }
  }
  size_t base = (size_t)pix * 128 + chq * 32;
  float inv = 1.f / (cnt + 1e-10f);
#pragma unroll
  for (int i = 0; i < 32; ++i)
    out[base + i] = x[base + i] + (acc[i] + cnt * bout[chq * 32 + i]) * inv;
}

extern "C" void kernel_launch(void* const* d_in, const int* in_sizes, int n_in,
                              void* d_out, int out_size, void* d_ws, size_t ws_size,
                              hipStream_t stream) {
  const float* x    = (const float*)d_in[0];
  const float* prob = (const float*)d_in[1];
  const float* fixw = (const float*)d_in[2];
  const float* wqkv = (const float*)d_in[3];
  const float* wout = (const float*)d_in[4];
  const float* bout = (const float*)d_in[5];
  float* out = (float*)d_out;
  float* ws  = (float*)d_ws;
  if (ws_size < WS_FLOATS * sizeof(float)) return;  /* need ~27.2 MB scratch */

  float* ent  = ws + OFF_ENT;
  float* sc   = ws + OFF_SCORE;
  int*   keep = (int*)(ws + OFF_KEEP);
  unsigned short* wqkv_bf = (unsigned short*)(ws + OFF_WQKV);
  unsigned short* wout_bf = (unsigned short*)(ws + OFF_WOUT);
  unsigned short* tokbf   = (unsigned short*)(ws + OFF_TOKBF);
  unsigned short* po      = (unsigned short*)(ws + OFF_PO);

  k_entropy<<<256, 256, 0, stream>>>(prob, ent);
  k_score<<<(NB * NBOX + 255) / 256, 256, 0, stream>>>(ent, fixw, sc);
  k_wcvt<<<1024, 256, 0, stream>>>(wqkv, wout, wqkv_bf, wout_bf);
  k_nms<<<NB, 64, 0, stream>>>(sc, keep);
  k_toks<<<NWTOT, 256, 0, stream>>>(x, keep, tokbf);
  k_attn<<<NWTOT, 512, 0, stream>>>(tokbf, wqkv_bf, wout_bf, po);
  k_final<<<NB * 65536 * 4 / 256, 256, 0, stream>>>(x, po, keep, bout, out);
}

// Round 7
// 486.722 us; speedup vs baseline: 9.7216x; 1.0636x over previous
//
#include <hip/hip_runtime.h>
#include <math.h>

#define NB 4
#define NWIN 121
#define NBOX (NWIN*NWIN)   /* 14641 */
#define NKEEP 50
#define HWD 256
#define DIM 128
#define HEADS 8
#define NTOK 256
#define NWTOT (NB*NKEEP)   /* 200 */

/* ws layout (float units) */
#define OFF_ENT   0          /* 65536 */
#define OFF_SCORE 65536      /* 58564 */
#define OFF_KEEP  124160     /* 400 B = 100 floats */
#define OFF_WQKV  124288     /* 196608 ushort = 98304 f */
#define OFF_WOUT  222592     /* 65536 ushort = 32768 f */
#define OFF_TOKBF 255360     /* 6553600 ushort = 3276800 f */
#define OFF_PO    3532160    /* 6553600 ushort = 3276800 f */
#define WS_FLOATS 6808960

#define KPAD 76
#define VPAD 268

typedef __attribute__((ext_vector_type(8))) short short8;
typedef __attribute__((ext_vector_type(4))) short short4v;
typedef __attribute__((ext_vector_type(4))) float f32x4;

static __device__ __forceinline__ unsigned short f2bf(float f) {
  union { float f; unsigned u; } v; v.f = f;
  unsigned r = (v.u + 0x7fffu + ((v.u >> 16) & 1u)) >> 16;
  return (unsigned short)r;
}
static __device__ __forceinline__ short4v pk4(f32x4 a) {
  short4v r;
  r[0] = (short)f2bf(a[0]); r[1] = (short)f2bf(a[1]);
  r[2] = (short)f2bf(a[2]); r[3] = (short)f2bf(a[3]);
  return r;
}
static __device__ __forceinline__ short8 ld8_lds(const unsigned short* p) {
  short4v a = *(const short4v*)p;
  short4v b = *(const short4v*)(p + 4);
  short8 r;
  r[0]=a[0]; r[1]=a[1]; r[2]=a[2]; r[3]=a[3];
  r[4]=b[0]; r[5]=b[1]; r[6]=b[2]; r[7]=b[3];
  return r;
}
static __device__ __forceinline__ short8 ld8_g(const unsigned short* p) {
  return *(const short8*)p;   /* 16B-aligned global */
}

template<int CTRL>
static __device__ __forceinline__ float dppmax(float v) {
  union { float f; int i; } a, r; a.f = v;
  /* old = own value -> bound lanes keep own value = identity for max */
  r.i = __builtin_amdgcn_update_dpp(a.i, a.i, CTRL, 0xf, 0xf, false);
  return fmaxf(v, r.f);
}

__global__ void k_entropy(const float* __restrict__ prob, float* __restrict__ ent) {
  int idx = blockIdx.x * 256 + threadIdx.x;
  int b = idx >> 14, p = idx & 16383;
  float p0 = prob[(size_t)(b * 2) * 16384 + p];
  float p1 = prob[(size_t)(b * 2 + 1) * 16384 + p];
  ent[idx] = -(p0 * log2f(p0 + 1e-10f) + p1 * log2f(p1 + 1e-10f));
}

__global__ void k_score(const float* __restrict__ ent, const float* __restrict__ fw,
                        float* __restrict__ sc) {
  int gid = blockIdx.x * 256 + threadIdx.x;
  if (gid >= NB * NBOX) return;
  int b = gid / NBOX, rem = gid % NBOX;
  int oy = rem / NWIN, ox = rem % NWIN;
  const float* e = ent + b * 16384 + oy * 128 + ox;
  float s = 0.f;
#pragma unroll
  for (int r = 0; r < 8; ++r)
#pragma unroll
    for (int c = 0; c < 8; ++c)
      s += e[r * 128 + c] * fw[r * 8 + c];
  sc[gid] = s * (1.0f / 64.0f);
}

/* Single-wave NMS v3: DPP wave-max argmax (no ds_bpermute on the critical
   path), per-lane row ownership (lane l owns rows l and l+64), XOR-swizzled
   LDS tile (col ^ ((row&7)<<2)) so row scans run at the b128 floor.
   Integer inter>75 test is bit-equivalent to the fp32 IoU (products of odd
   {7..15}^2 never equal 75). Lockstep wave, no barriers -> deterministic. */
__global__ void k_nms(const float* __restrict__ scores, int* __restrict__ keep) {
  __shared__ float sc[NWIN * 128];
  int b = blockIdx.x, l = threadIdx.x;   /* 64 lanes */
  for (int idx = l; idx < NWIN * 128; idx += 64) {
    int r = idx >> 7, c = idx & 127;
    float v = (c < NWIN) ? scores[b * NBOX + r * NWIN + c] : -INFINITY;
    sc[(r << 7) + (c ^ ((r & 7) << 2))] = v;
  }
  /* init row maxima (scan in logical-block order; strict > = lowest col) */
  float M0 = -INFINITY, M1 = -INFINITY; int C0 = 0, C1 = 0;
#pragma unroll
  for (int slot = 0; slot < 2; ++slot) {
    int r = l + slot * 64;
    if (slot == 1 && r >= NWIN) break;
    int r7 = (r & 7) << 2, rbase = r << 7;
    float bv0=-INFINITY,bv1=-INFINITY,bv2=-INFINITY,bv3=-INFINITY;
    int bc0=0,bc1=0,bc2=0,bc3=0;
    for (int lb = 0; lb < 32; ++lb) {
      f32x4 v = *(const f32x4*)&sc[rbase + ((lb << 2) ^ r7)];
      int c0 = lb << 2;
      if (v[0] > bv0) { bv0 = v[0]; bc0 = c0; }
      if (v[1] > bv1) { bv1 = v[1]; bc1 = c0 + 1; }
      if (v[2] > bv2) { bv2 = v[2]; bc2 = c0 + 2; }
      if (v[3] > bv3) { bv3 = v[3]; bc3 = c0 + 3; }
    }
    float bv = bv0; int bc = bc0;
    if (bv1 > bv || (bv1 == bv && bc1 < bc)) { bv = bv1; bc = bc1; }
    if (bv2 > bv || (bv2 == bv && bc2 < bc)) { bv = bv2; bc = bc2; }
    if (bv3 > bv || (bv3 == bv && bc3 < bc)) { bv = bv3; bc = bc3; }
    if (slot == 0) { M0 = bv; C0 = bc; } else { M1 = bv; C1 = bc; }
  }

  for (int k = 0; k < NKEEP; ++k) {
    /* wave argmax via DPP max + ballot (scores >= 0 > -INF pads) */
    float g = fmaxf(M0, M1);
    g = dppmax<0x111>(g); g = dppmax<0x112>(g);
    g = dppmax<0x114>(g); g = dppmax<0x118>(g);
    g = dppmax<0x142>(g); g = dppmax<0x143>(g);
    union { float f; int i; } gi, gm; gi.f = g;
    gm.i = __builtin_amdgcn_readlane(gi.i, 63);
    float gmax = gm.f;
    unsigned long long b0 = __ballot(M0 == gmax);
    unsigned long long b1 = __ballot(M1 == gmax);
    int R;
    if (b0) R = __ffsll((unsigned long long)b0) - 1;
    else    R = 64 + __ffsll((unsigned long long)b1) - 1;
    int Cc = (R < 64) ? __builtin_amdgcn_readlane(C0, R)
                      : __builtin_amdgcn_readlane(C1, R - 64);
    if (l == 0) {
      keep[(b * NKEEP + k) * 2 + 0] = 2 * R;   /* sy */
      keep[(b * NKEEP + k) * 2 + 1] = 2 * Cc;  /* sx */
    }
    /* suppression by row owners + killed-cache detection */
    bool kill0 = false, kill1 = false;
    {
      int dy = l - R, ady = dy < 0 ? -dy : dy;
      if (ady <= 4) {
        int ih = 15 - 2 * ady;
#pragma unroll
        for (int dx = -4; dx <= 4; ++dx) {
          int adx = dx < 0 ? -dx : dx;
          if ((15 - 2 * adx) * ih > 75) {
            int cc = Cc + dx;
            if ((unsigned)cc < (unsigned)NWIN)
              sc[(l << 7) + (cc ^ ((l & 7) << 2))] = -INFINITY;
          }
        }
        int adx = C0 - Cc; adx = adx < 0 ? -adx : adx;
        kill0 = (adx <= 4) && ((15 - 2 * adx) * ih > 75);
      }
    }
    if (l + 64 < NWIN) {
      int r1 = l + 64;
      int dy = r1 - R, ady = dy < 0 ? -dy : dy;
      if (ady <= 4) {
        int ih = 15 - 2 * ady;
#pragma unroll
        for (int dx = -4; dx <= 4; ++dx) {
          int adx = dx < 0 ? -dx : dx;
          if ((15 - 2 * adx) * ih > 75) {
            int cc = Cc + dx;
            if ((unsigned)cc < (unsigned)NWIN)
              sc[(r1 << 7) + (cc ^ ((r1 & 7) << 2))] = -INFINITY;
          }
        }
        int adx = C1 - Cc; adx = adx < 0 ? -adx : adx;
        kill1 = (adx <= 4) && ((15 - 2 * adx) * ih > 75);
      }
    }
    /* parallel repair: each killed row rescanned by its owner lane
       (at most one slot per lane can be killed: rows differ by 64) */
    if (__any(kill0 | kill1)) {
      int r = kill0 ? l : (kill1 ? l + 64 : l);   /* safe row for idle lanes */
      int r7 = (r & 7) << 2, rbase = r << 7;
      float bv0=-INFINITY,bv1=-INFINITY,bv2=-INFINITY,bv3=-INFINITY;
      int bc0=0,bc1=0,bc2=0,bc3=0;
      for (int lb = 0; lb < 32; ++lb) {
        f32x4 v = *(const f32x4*)&sc[rbase + ((lb << 2) ^ r7)];
        int c0 = lb << 2;
        if (v[0] > bv0) { bv0 = v[0]; bc0 = c0; }
        if (v[1] > bv1) { bv1 = v[1]; bc1 = c0 + 1; }
        if (v[2] > bv2) { bv2 = v[2]; bc2 = c0 + 2; }
        if (v[3] > bv3) { bv3 = v[3]; bc3 = c0 + 3; }
      }
      float bv = bv0; int bc = bc0;
      if (bv1 > bv || (bv1 == bv && bc1 < bc)) { bv = bv1; bc = bc1; }
      if (bv2 > bv || (bv2 == bv && bc2 < bc)) { bv = bv2; bc = bc2; }
      if (bv3 > bv || (bv3 == bv && bc3 < bc)) { bv = bv3; bc = bc3; }
      if (kill0) { M0 = bv; C0 = bc; }
      else if (kill1) { M1 = bv; C1 = bc; }
    }
  }
}

__global__ void k_wcvt(const float* __restrict__ wqkv, const float* __restrict__ wout,
                       unsigned short* __restrict__ wqkv_bf, unsigned short* __restrict__ wout_bf) {
  int i = blockIdx.x * 256 + threadIdx.x;
  if (i < 196608) wqkv_bf[i] = f2bf(wqkv[i]);
  int j = i - 196608;
  if (j >= 0 && j < 65536) wout_bf[j] = f2bf(wout[j]);
}

__global__ void k_toks(const float* __restrict__ x, const int* __restrict__ keep,
                       unsigned short* __restrict__ tokbf) {
  int w = blockIdx.x;
  int b = w / NKEEP;
  int sy = keep[w * 2 + 0], sx = keep[w * 2 + 1];
  int tid = threadIdx.x;
  int ch = tid & 127, th = tid >> 7;
  const float* xb = x + (size_t)b * 65536 * DIM;
  for (int it = 0; it < 128; ++it) {
    int tk = it * 2 + th;
    int i = tk >> 4, j = tk & 15;
    float offy = (i + 0.5f) * 0.9375f;
    float offx = (j + 0.5f) * 0.9375f;
    int li = (int)offy, lj = (int)offx;
    float fy = offy - (float)li, fx = offx - (float)lj;
    const float* p = xb + ((size_t)((sy + li) * HWD + (sx + lj))) * DIM + ch;
    float v00 = p[0], v01 = p[DIM], v10 = p[HWD * DIM], v11 = p[HWD * DIM + DIM];
    float w00 = (1.f - fy) * (1.f - fx), w01 = (1.f - fy) * fx;
    float w10 = fy * (1.f - fx), w11 = fy * fx;
    tokbf[((size_t)w * NTOK + tk) * DIM + ch] = f2bf(w00 * v00 + w01 * v01 + w10 * v10 + w11 * v11);
  }
}

/* Per-window fused attention (proven R5/R6). 8 waves; head loop outer. */
__global__ __launch_bounds__(512, 2) void k_attn(
    const unsigned short* __restrict__ tokbf,
    const unsigned short* __restrict__ wqkv,
    const unsigned short* __restrict__ wout,
    unsigned short* __restrict__ po) {
  __shared__ __align__(16) char smem[112128];
  unsigned short* Klds = (unsigned short*)smem;             /* [256][KPAD] */
  unsigned short* VT   = (unsigned short*)(smem + 38912);   /* [64][VPAD] */
  const int tid = threadIdx.x;
  const int wv = tid >> 6, ln = tid & 63;
  const int lo = ln & 15, hi = ln >> 4;
  const int win = blockIdx.x;
  unsigned short* QP = (unsigned short*)(smem + 73216 + wv * 4864);  /* [32][KPAD] */
  const unsigned short* tw = tokbf + (size_t)win * NTOK * DIM;
  const int qrow = wv * 32;

  f32x4 pacc[8][2];
#pragma unroll
  for (int mf = 0; mf < 8; ++mf)
#pragma unroll
    for (int nf = 0; nf < 2; ++nf) pacc[mf][nf] = (f32x4){0.f,0.f,0.f,0.f};

  for (int h = 0; h < HEADS; ++h) {
    if (h) __syncthreads();

    /* K stage */
    {
      f32x4 kacc[4][2];
#pragma unroll
      for (int mf = 0; mf < 4; ++mf)
#pragma unroll
        for (int nf = 0; nf < 2; ++nf) kacc[mf][nf] = (f32x4){0.f,0.f,0.f,0.f};
#pragma unroll
      for (int kf = 0; kf < 4; ++kf) {
        short8 aw[4], bt[2];
#pragma unroll
        for (int mf = 0; mf < 4; ++mf)
          aw[mf] = ld8_g(wqkv + (size_t)(512 + h * 64 + mf * 16 + lo) * 128 + kf * 32 + hi * 8);
#pragma unroll
        for (int nf = 0; nf < 2; ++nf)
          bt[nf] = ld8_g(&tw[(qrow + nf * 16 + lo) * 128 + kf * 32 + hi * 8]);
#pragma unroll
        for (int mf = 0; mf < 4; ++mf)
#pragma unroll
          for (int nf = 0; nf < 2; ++nf)
            kacc[mf][nf] = __builtin_amdgcn_mfma_f32_16x16x32_bf16(aw[mf], bt[nf], kacc[mf][nf], 0, 0, 0);
      }
#pragma unroll
      for (int mf = 0; mf < 4; ++mf)
#pragma unroll
        for (int nf = 0; nf < 2; ++nf)
          *(short4v*)&Klds[(qrow + nf * 16 + lo) * KPAD + mf * 16 + hi * 4] = pk4(kacc[mf][nf]);
    }
    /* V stage */
    {
      f32x4 vacc[2][4];
#pragma unroll
      for (int mf = 0; mf < 2; ++mf)
#pragma unroll
        for (int nf = 0; nf < 4; ++nf) vacc[mf][nf] = (f32x4){0.f,0.f,0.f,0.f};
#pragma unroll
      for (int kf = 0; kf < 4; ++kf) {
        short8 at[2], bw[4];
#pragma unroll
        for (int mf = 0; mf < 2; ++mf)
          at[mf] = ld8_g(&tw[(qrow + mf * 16 + lo) * 128 + kf * 32 + hi * 8]);
#pragma unroll
        for (int nf = 0; nf < 4; ++nf)
          bw[nf] = ld8_g(wqkv + (size_t)(1024 + h * 64 + nf * 16 + lo) * 128 + kf * 32 + hi * 8);
#pragma unroll
        for (int mf = 0; mf < 2; ++mf)
#pragma unroll
          for (int nf = 0; nf < 4; ++nf)
            vacc[mf][nf] = __builtin_amdgcn_mfma_f32_16x16x32_bf16(at[mf], bw[nf], vacc[mf][nf], 0, 0, 0);
      }
#pragma unroll
      for (int mf = 0; mf < 2; ++mf)
#pragma unroll
        for (int nf = 0; nf < 4; ++nf)
          *(short4v*)&VT[(nf * 16 + lo) * VPAD + qrow + mf * 16 + hi * 4] = pk4(vacc[mf][nf]);
    }
    /* Q stage */
    {
      f32x4 qacc[4][2];
#pragma unroll
      for (int mf = 0; mf < 4; ++mf)
#pragma unroll
        for (int nf = 0; nf < 2; ++nf) qacc[mf][nf] = (f32x4){0.f,0.f,0.f,0.f};
#pragma unroll
      for (int kf = 0; kf < 4; ++kf) {
        short8 aw[4], bt[2];
#pragma unroll
        for (int mf = 0; mf < 4; ++mf)
          aw[mf] = ld8_g(wqkv + (size_t)(h * 64 + mf * 16 + lo) * 128 + kf * 32 + hi * 8);
#pragma unroll
        for (int nf = 0; nf < 2; ++nf)
          bt[nf] = ld8_g(&tw[(qrow + nf * 16 + lo) * 128 + kf * 32 + hi * 8]);
#pragma unroll
        for (int mf = 0; mf < 4; ++mf)
#pragma unroll
          for (int nf = 0; nf < 2; ++nf)
            qacc[mf][nf] = __builtin_amdgcn_mfma_f32_16x16x32_bf16(aw[mf], bt[nf], qacc[mf][nf], 0, 0, 0);
      }
#pragma unroll
      for (int mf = 0; mf < 4; ++mf)
#pragma unroll
        for (int nf = 0; nf < 2; ++nf)
          *(short4v*)&QP[(nf * 16 + lo) * KPAD + mf * 16 + hi * 4] = pk4(qacc[mf][nf] * 0.125f);
    }
    __syncthreads();

    short8 Qb[2][2];
#pragma unroll
    for (int nf = 0; nf < 2; ++nf)
#pragma unroll
      for (int kf = 0; kf < 2; ++kf)
        Qb[nf][kf] = ld8_lds(&QP[(nf * 16 + lo) * KPAD + kf * 32 + hi * 8]);

    f32x4 Ot[4][2];
#pragma unroll
    for (int mf = 0; mf < 4; ++mf)
#pragma unroll
      for (int nf = 0; nf < 2; ++nf) Ot[mf][nf] = (f32x4){0.f,0.f,0.f,0.f};
    float mrow[2] = {-INFINITY, -INFINITY};
    float lrow[2] = {0.f, 0.f};

    for (int ck = 0; ck < 4; ++ck) {
      f32x4 sacc[4][2];
#pragma unroll
      for (int mf = 0; mf < 4; ++mf)
#pragma unroll
        for (int nf = 0; nf < 2; ++nf) sacc[mf][nf] = (f32x4){0.f,0.f,0.f,0.f};
      short8 ka[4][2];
#pragma unroll
      for (int mf = 0; mf < 4; ++mf)
#pragma unroll
        for (int kf = 0; kf < 2; ++kf)
          ka[mf][kf] = ld8_lds(&Klds[(ck * 64 + mf * 16 + lo) * KPAD + kf * 32 + hi * 8]);
#pragma unroll
      for (int mf = 0; mf < 4; ++mf)
#pragma unroll
        for (int nf = 0; nf < 2; ++nf)
#pragma unroll
          for (int kf = 0; kf < 2; ++kf)
            sacc[mf][nf] = __builtin_amdgcn_mfma_f32_16x16x32_bf16(ka[mf][kf], Qb[nf][kf], sacc[mf][nf], 0, 0, 0);

#pragma unroll
      for (int nf = 0; nf < 2; ++nf) {
        float cmax = -INFINITY;
#pragma unroll
        for (int mf = 0; mf < 4; ++mf)
#pragma unroll
          for (int r = 0; r < 4; ++r) cmax = fmaxf(cmax, sacc[mf][nf][r]);
        cmax = fmaxf(cmax, __shfl_xor(cmax, 16));
        cmax = fmaxf(cmax, __shfl_xor(cmax, 32));
        float mnew = fmaxf(mrow[nf], cmax);
        float corr = __expf(mrow[nf] - mnew);
        float ps = 0.f;
#pragma unroll
        for (int mf = 0; mf < 4; ++mf)
#pragma unroll
          for (int r = 0; r < 4; ++r) {
            float e = __expf(sacc[mf][nf][r] - mnew);
            sacc[mf][nf][r] = e; ps += e;
          }
        ps += __shfl_xor(ps, 16);
        ps += __shfl_xor(ps, 32);
        lrow[nf] = lrow[nf] * corr + ps;
        mrow[nf] = mnew;
#pragma unroll
        for (int mf = 0; mf < 4; ++mf) Ot[mf][nf] *= corr;
      }
#pragma unroll
      for (int mf = 0; mf < 4; ++mf)
#pragma unroll
        for (int nf = 0; nf < 2; ++nf)
          *(short4v*)&QP[(nf * 16 + lo) * KPAD + mf * 16 + hi * 4] = pk4(sacc[mf][nf]);
      short8 pb[2][2], va[4][2];
#pragma unroll
      for (int nf = 0; nf < 2; ++nf)
#pragma unroll
        for (int kf = 0; kf < 2; ++kf)
          pb[nf][kf] = ld8_lds(&QP[(nf * 16 + lo) * KPAD + kf * 32 + hi * 8]);
#pragma unroll
      for (int mf = 0; mf < 4; ++mf)
#pragma unroll
        for (int kf = 0; kf < 2; ++kf)
          va[mf][kf] = ld8_lds(&VT[(mf * 16 + lo) * VPAD + ck * 64 + kf * 32 + hi * 8]);
#pragma unroll
      for (int mf = 0; mf < 4; ++mf)
#pragma unroll
        for (int nf = 0; nf < 2; ++nf)
#pragma unroll
          for (int kf = 0; kf < 2; ++kf)
            Ot[mf][nf] = __builtin_amdgcn_mfma_f32_16x16x32_bf16(va[mf][kf], pb[nf][kf], Ot[mf][nf], 0, 0, 0);
    }

#pragma unroll
    for (int nf = 0; nf < 2; ++nf) {
      float inv = 1.f / lrow[nf];
#pragma unroll
      for (int mf = 0; mf < 4; ++mf)
        *(short4v*)&QP[(nf * 16 + lo) * KPAD + mf * 16 + hi * 4] = pk4(Ot[mf][nf] * inv);
    }
    short8 Ob[2][2];
#pragma unroll
    for (int nf = 0; nf < 2; ++nf)
#pragma unroll
      for (int kf = 0; kf < 2; ++kf)
        Ob[nf][kf] = ld8_lds(&QP[(nf * 16 + lo) * KPAD + kf * 32 + hi * 8]);
#pragma unroll
    for (int kf = 0; kf < 2; ++kf) {
      short8 aw[8];
#pragma unroll
      for (int mf = 0; mf < 8; ++mf)
        aw[mf] = ld8_g(wout + (size_t)(mf * 16 + lo) * 512 + h * 64 + kf * 32 + hi * 8);
#pragma unroll
      for (int mf = 0; mf < 8; ++mf)
#pragma unroll
        for (int nf = 0; nf < 2; ++nf)
          pacc[mf][nf] = __builtin_amdgcn_mfma_f32_16x16x32_bf16(aw[mf], Ob[nf][kf], pacc[mf][nf], 0, 0, 0);
    }
  }

#pragma unroll
  for (int mf = 0; mf < 8; ++mf)
#pragma unroll
    for (int nf = 0; nf < 2; ++nf)
      *(short4v*)&po[((size_t)win * NTOK + qrow + nf * 16 + lo) * 128 + mf * 16 + hi * 4] = pk4(pacc[mf][nf]);
}

/* Gather finalize: thread = (pixel, 32-ch quarter); loops 50 windows. */
__global__ void k_final(const float* __restrict__ x, const unsigned short* __restrict__ po,
                        const int* __restrict__ keep, const float* __restrict__ bout,
                        float* __restrict__ out) {
  __shared__ int kp[2 * NKEEP];
  int tid = threadIdx.x;
  int gid = blockIdx.x * 256 + tid;
  int chq = gid & 3, pix = gid >> 2;
  int b = pix >> 16, pb = pix & 65535, y = pb >> 8, xx = pb & 255;
  if (tid < 2 * NKEEP) kp[tid] = keep[b * 2 * NKEEP + tid];
  __syncthreads();
  float acc[32];
#pragma unroll
  for (int i = 0; i < 32; ++i) acc[i] = 0.f;
  float cnt = 0.f;
  for (int w = 0; w < NKEEP; ++w) {
    int dy = y - kp[2 * w], dx = xx - kp[2 * w + 1];
    if ((unsigned)dy < 16u && (unsigned)dx < 16u) {
      cnt += 1.f;
      const unsigned short* pp = po + ((size_t)(b * NKEEP + w) * NTOK + dy * 16 + dx) * 128 + chq * 32;
#pragma unroll
      for (int k2 = 0; k2 < 4; ++k2) {
        short8 v = ld8_g(pp + k2 * 8);
#pragma unroll
        for (int j = 0; j < 8; ++j) {
          union { unsigned u; float f; } cv;
          cv.u = ((unsigned)(unsigned short)v[j]) << 16;
          acc[k2 * 8 + j] += cv.f;
        }
      }
    }
  }
  size_t base = (size_t)pix * 128 + chq * 32;
  float inv = 1.f / (cnt + 1e-10f);
#pragma unroll
  for (int i = 0; i < 32; ++i)
    out[base + i] = x[base + i] + (acc[i] + cnt * bout[chq * 32 + i]) * inv;
}

extern "C" void kernel_launch(void* const* d_in, const int* in_sizes, int n_in,
                              void* d_out, int out_size, void* d_ws, size_t ws_size,
                              hipStream_t stream) {
  const float* x    = (const float*)d_in[0];
  const float* prob = (const float*)d_in[1];
  const float* fixw = (const float*)d_in[2];
  const float* wqkv = (const float*)d_in[3];
  const float* wout = (const float*)d_in[4];
  const float* bout = (const float*)d_in[5];
  float* out = (float*)d_out;
  float* ws  = (float*)d_ws;
  if (ws_size < WS_FLOATS * sizeof(float)) return;  /* need ~27.2 MB scratch */

  float* ent  = ws + OFF_ENT;
  float* sc   = ws + OFF_SCORE;
  int*   keep = (int*)(ws + OFF_KEEP);
  unsigned short* wqkv_bf = (unsigned short*)(ws + OFF_WQKV);
  unsigned short* wout_bf = (unsigned short*)(ws + OFF_WOUT);
  unsigned short* tokbf   = (unsigned short*)(ws + OFF_TOKBF);
  unsigned short* po      = (unsigned short*)(ws + OFF_PO);

  k_entropy<<<256, 256, 0, stream>>>(prob, ent);
  k_score<<<(NB * NBOX + 255) / 256, 256, 0, stream>>>(ent, fixw, sc);
  k_wcvt<<<1024, 256, 0, stream>>>(wqkv, wout, wqkv_bf, wout_bf);
  k_nms<<<NB, 64, 0, stream>>>(sc, keep);
  k_toks<<<NWTOT, 256, 0, stream>>>(x, keep, tokbf);
  k_attn<<<NWTOT, 512, 0, stream>>>(tokbf, wqkv_bf, wout_bf, po);
  k_final<<<NB * 65536 * 4 / 256, 256, 0, stream>>>(x, po, keep, bout, out);
}

// Round 8
// 390.202 us; speedup vs baseline: 12.1264x; 1.2474x over previous
//
#include <hip/hip_runtime.h>
#include <math.h>

#define NB 4
#define NWIN 121
#define NBOX (NWIN*NWIN)   /* 14641 */
#define NKEEP 50
#define HWD 256
#define DIM 128
#define HEADS 8
#define NTOK 256
#define NWTOT (NB*NKEEP)   /* 200 */
#define SCPAD 15616        /* 122 rows x 128 cols, swizzled, per batch */

/* ws layout (float units) */
#define OFF_ENT   0          /* 65536 */
#define OFF_SCORE 65536      /* NB*SCPAD = 62464 */
#define OFF_KEEP  128128     /* 100 floats */
#define OFF_WQKV  128256     /* 98304 f */
#define OFF_WOUT  226560     /* 32768 f */
#define OFF_TOKBF 259328     /* 3276800 f */
#define OFF_PO    3536128    /* 3276800 f */
#define WS_FLOATS 6812928

#define KPAD 76
#define VPAD 268

typedef __attribute__((ext_vector_type(8))) short short8;
typedef __attribute__((ext_vector_type(4))) short short4v;
typedef __attribute__((ext_vector_type(4))) float f32x4;

static __device__ __forceinline__ unsigned short f2bf(float f) {
  union { float f; unsigned u; } v; v.f = f;
  unsigned r = (v.u + 0x7fffu + ((v.u >> 16) & 1u)) >> 16;
  return (unsigned short)r;
}
static __device__ __forceinline__ short4v pk4(f32x4 a) {
  short4v r;
  r[0] = (short)f2bf(a[0]); r[1] = (short)f2bf(a[1]);
  r[2] = (short)f2bf(a[2]); r[3] = (short)f2bf(a[3]);
  return r;
}
static __device__ __forceinline__ short8 ld8_lds(const unsigned short* p) {
  short4v a = *(const short4v*)p;
  short4v b = *(const short4v*)(p + 4);
  short8 r;
  r[0]=a[0]; r[1]=a[1]; r[2]=a[2]; r[3]=a[3];
  r[4]=b[0]; r[5]=b[1]; r[6]=b[2]; r[7]=b[3];
  return r;
}
static __device__ __forceinline__ short8 ld8_g(const unsigned short* p) {
  return *(const short8*)p;   /* 16B-aligned global */
}

template<int CTRL>
static __device__ __forceinline__ float dppmax(float v) {
  union { float f; int i; } a, r; a.f = v;
  r.i = __builtin_amdgcn_update_dpp(a.i, a.i, CTRL, 0xf, 0xf, false);
  return fmaxf(v, r.f);
}
/* full-wave max -> all lanes (via readlane 63 after chain) */
static __device__ __forceinline__ float wavemax(float v) {
  v = dppmax<0x111>(v); v = dppmax<0x112>(v);
  v = dppmax<0x114>(v); v = dppmax<0x118>(v);
  v = dppmax<0x142>(v); v = dppmax<0x143>(v);
  union { float f; int i; } gi, gm; gi.f = v;
  gm.i = __builtin_amdgcn_readlane(gi.i, 63);
  return gm.f;
}

__global__ void k_entropy(const float* __restrict__ prob, float* __restrict__ ent) {
  int idx = blockIdx.x * 256 + threadIdx.x;
  int b = idx >> 14, p = idx & 16383;
  float p0 = prob[(size_t)(b * 2) * 16384 + p];
  float p1 = prob[(size_t)(b * 2 + 1) * 16384 + p];
  ent[idx] = -(p0 * log2f(p0 + 1e-10f) + p1 * log2f(p1 + 1e-10f));
}

/* conv score, written PADDED (128 cols, -INF pads) and XOR-swizzled
   (col ^ ((row&7)<<2)) so k_nms can bulk-copy and scan vector-aligned. */
__global__ void k_score(const float* __restrict__ ent, const float* __restrict__ fw,
                        float* __restrict__ scp) {
  int gid = blockIdx.x * 256 + threadIdx.x;
  if (gid >= NB * SCPAD) return;
  int b = gid / SCPAD, idx = gid % SCPAD;
  int r = idx >> 7, c = idx & 127;
  float s = -INFINITY;
  if (r < NWIN && c < NWIN) {
    const float* e = ent + b * 16384 + r * 128 + c;
    float a = 0.f;
#pragma unroll
    for (int rr = 0; rr < 8; ++rr)
#pragma unroll
      for (int cc = 0; cc < 8; ++cc)
        a += e[rr * 128 + cc] * fw[rr * 8 + cc];
    s = a * (1.0f / 64.0f);
  }
  scp[b * SCPAD + (r << 7) + (c ^ ((r & 7) << 2))] = s;
}

/* Single-wave NMS v4: vectorized pipelined init copy (no serial
   load->LDS-write chain), register row-max cache, DPP argmax,
   owner-lane suppression, cooperative per-killed-row repair.
   Lockstep wave, no barriers -> deterministic. */
__global__ void k_nms(const float* __restrict__ scp, int* __restrict__ keep) {
  __shared__ float sc[SCPAD];
  int b = blockIdx.x, l = threadIdx.x;   /* 64 lanes */
  const float* src = scp + b * SCPAD;
  /* staged copy: 61 f32x4 per lane, 8 loads in flight per chunk */
  for (int cb = 0; cb < 64; cb += 8) {
    f32x4 t[8];
#pragma unroll
    for (int i = 0; i < 8; ++i) {
      int idx = (cb + i) * 256 + l * 4;
      if (idx < SCPAD) t[i] = *(const f32x4*)&src[idx];
    }
#pragma unroll
    for (int i = 0; i < 8; ++i) {
      int idx = (cb + i) * 256 + l * 4;
      if (idx < SCPAD) *(f32x4*)&sc[idx] = t[i];
    }
  }
  /* init row maxima -> registers (vector scan, swizzled) */
  float M0 = -INFINITY, M1 = -INFINITY; int C0 = 0, C1 = 0;
#pragma unroll
  for (int slot = 0; slot < 2; ++slot) {
    int r = l + slot * 64;
    if (slot == 1 && r >= NWIN) break;
    int r7 = (r & 7) << 2, rbase = r << 7;
    float bv0=-INFINITY,bv1=-INFINITY,bv2=-INFINITY,bv3=-INFINITY;
    int bc0=0,bc1=0,bc2=0,bc3=0;
    for (int lb = 0; lb < 32; ++lb) {
      f32x4 v = *(const f32x4*)&sc[rbase + ((lb << 2) ^ r7)];
      int c0 = lb << 2;
      if (v[0] > bv0) { bv0 = v[0]; bc0 = c0; }
      if (v[1] > bv1) { bv1 = v[1]; bc1 = c0 + 1; }
      if (v[2] > bv2) { bv2 = v[2]; bc2 = c0 + 2; }
      if (v[3] > bv3) { bv3 = v[3]; bc3 = c0 + 3; }
    }
    float bv = bv0; int bc = bc0;
    if (bv1 > bv || (bv1 == bv && bc1 < bc)) { bv = bv1; bc = bc1; }
    if (bv2 > bv || (bv2 == bv && bc2 < bc)) { bv = bv2; bc = bc2; }
    if (bv3 > bv || (bv3 == bv && bc3 < bc)) { bv = bv3; bc = bc3; }
    if (slot == 0) { M0 = bv; C0 = bc; } else { M1 = bv; C1 = bc; }
  }

  for (int k = 0; k < NKEEP; ++k) {
    /* argmax: DPP wave-max + ballot (lowest row wins ties) */
    float gmax = wavemax(fmaxf(M0, M1));
    unsigned long long b0 = __ballot(M0 == gmax);
    unsigned long long b1 = __ballot(M1 == gmax);
    int R;
    if (b0) R = __ffsll((unsigned long long)b0) - 1;
    else    R = 64 + __ffsll((unsigned long long)b1) - 1;
    int Cc = (R < 64) ? __builtin_amdgcn_readlane(C0, R)
                      : __builtin_amdgcn_readlane(C1, R - 64);
    if (l == 0) {
      keep[(b * NKEEP + k) * 2 + 0] = 2 * R;   /* sy */
      keep[(b * NKEEP + k) * 2 + 1] = 2 * Cc;  /* sx */
    }
    /* suppression by row owners + killed-cache detection */
    bool kill0 = false, kill1 = false;
    {
      int dy = l - R, ady = dy < 0 ? -dy : dy;
      if (ady <= 4) {
        int ih = 15 - 2 * ady;
#pragma unroll
        for (int dx = -4; dx <= 4; ++dx) {
          int adx = dx < 0 ? -dx : dx;
          if ((15 - 2 * adx) * ih > 75) {
            int cc = Cc + dx;
            if ((unsigned)cc < (unsigned)NWIN)
              sc[(l << 7) + (cc ^ ((l & 7) << 2))] = -INFINITY;
          }
        }
        int adx = C0 - Cc; adx = adx < 0 ? -adx : adx;
        kill0 = (adx <= 4) && ((15 - 2 * adx) * ih > 75);
      }
    }
    if (l + 64 < NWIN) {
      int r1 = l + 64;
      int dy = r1 - R, ady = dy < 0 ? -dy : dy;
      if (ady <= 4) {
        int ih = 15 - 2 * ady;
#pragma unroll
        for (int dx = -4; dx <= 4; ++dx) {
          int adx = dx < 0 ? -dx : dx;
          if ((15 - 2 * adx) * ih > 75) {
            int cc = Cc + dx;
            if ((unsigned)cc < (unsigned)NWIN)
              sc[(r1 << 7) + (cc ^ ((r1 & 7) << 2))] = -INFINITY;
          }
        }
        int adx = C1 - Cc; adx = adx < 0 ? -adx : adx;
        kill1 = (adx <= 4) && ((15 - 2 * adx) * ih > 75);
      }
    }
    /* cooperative repair: iterate killed rows; all 64 lanes rescan one row
       (2 conflict-free swizzled reads) + DPP max + slot-ordered ballots */
    unsigned long long need0 = __ballot(kill0);
    unsigned long long need1 = __ballot(kill1);
    while (need0 | need1) {
      int rr;
      if (need0) { rr = __ffsll((unsigned long long)need0) - 1; need0 &= need0 - 1; }
      else       { rr = __ffsll((unsigned long long)need1) - 1 + 64; need1 &= need1 - 1; }
      int r7 = (rr & 7) << 2, rbase = rr << 7;
      float v0 = sc[rbase + (l ^ r7)];          /* logical col l   */
      float v1 = sc[rbase + ((l + 64) ^ r7)];   /* logical col l+64 (pads -INF) */
      float rmax = wavemax(fmaxf(v0, v1));
      unsigned long long e0 = __ballot(v0 == rmax);
      unsigned long long e1 = __ballot(v1 == rmax);
      int bc;
      if (e0) bc = __ffsll((unsigned long long)e0) - 1;
      else    bc = 64 + __ffsll((unsigned long long)e1) - 1;
      if (l == (rr & 63)) {
        if (rr >= 64) { M1 = rmax; C1 = bc; }
        else          { M0 = rmax; C0 = bc; }
      }
    }
  }
}

__global__ void k_wcvt(const float* __restrict__ wqkv, const float* __restrict__ wout,
                       unsigned short* __restrict__ wqkv_bf, unsigned short* __restrict__ wout_bf) {
  int i = blockIdx.x * 256 + threadIdx.x;
  if (i < 196608) wqkv_bf[i] = f2bf(wqkv[i]);
  int j = i - 196608;
  if (j >= 0 && j < 65536) wout_bf[j] = f2bf(wout[j]);
}

__global__ void k_toks(const float* __restrict__ x, const int* __restrict__ keep,
                       unsigned short* __restrict__ tokbf) {
  int w = blockIdx.x;
  int b = w / NKEEP;
  int sy = keep[w * 2 + 0], sx = keep[w * 2 + 1];
  int tid = threadIdx.x;
  int ch = tid & 127, th = tid >> 7;
  const float* xb = x + (size_t)b * 65536 * DIM;
  for (int it = 0; it < 128; ++it) {
    int tk = it * 2 + th;
    int i = tk >> 4, j = tk & 15;
    float offy = (i + 0.5f) * 0.9375f;
    float offx = (j + 0.5f) * 0.9375f;
    int li = (int)offy, lj = (int)offx;
    float fy = offy - (float)li, fx = offx - (float)lj;
    const float* p = xb + ((size_t)((sy + li) * HWD + (sx + lj))) * DIM + ch;
    float v00 = p[0], v01 = p[DIM], v10 = p[HWD * DIM], v11 = p[HWD * DIM + DIM];
    float w00 = (1.f - fy) * (1.f - fx), w01 = (1.f - fy) * fx;
    float w10 = fy * (1.f - fx), w11 = fy * fx;
    tokbf[((size_t)w * NTOK + tk) * DIM + ch] = f2bf(w00 * v00 + w01 * v01 + w10 * v10 + w11 * v11);
  }
}

/* Per-window fused attention (proven R5-R7). 8 waves; head loop outer. */
__global__ __launch_bounds__(512, 2) void k_attn(
    const unsigned short* __restrict__ tokbf,
    const unsigned short* __restrict__ wqkv,
    const unsigned short* __restrict__ wout,
    unsigned short* __restrict__ po) {
  __shared__ __align__(16) char smem[112128];
  unsigned short* Klds = (unsigned short*)smem;             /* [256][KPAD] */
  unsigned short* VT   = (unsigned short*)(smem + 38912);   /* [64][VPAD] */
  const int tid = threadIdx.x;
  const int wv = tid >> 6, ln = tid & 63;
  const int lo = ln & 15, hi = ln >> 4;
  const int win = blockIdx.x;
  unsigned short* QP = (unsigned short*)(smem + 73216 + wv * 4864);  /* [32][KPAD] */
  const unsigned short* tw = tokbf + (size_t)win * NTOK * DIM;
  const int qrow = wv * 32;

  f32x4 pacc[8][2];
#pragma unroll
  for (int mf = 0; mf < 8; ++mf)
#pragma unroll
    for (int nf = 0; nf < 2; ++nf) pacc[mf][nf] = (f32x4){0.f,0.f,0.f,0.f};

  for (int h = 0; h < HEADS; ++h) {
    if (h) __syncthreads();

    /* K stage */
    {
      f32x4 kacc[4][2];
#pragma unroll
      for (int mf = 0; mf < 4; ++mf)
#pragma unroll
        for (int nf = 0; nf < 2; ++nf) kacc[mf][nf] = (f32x4){0.f,0.f,0.f,0.f};
#pragma unroll
      for (int kf = 0; kf < 4; ++kf) {
        short8 aw[4], bt[2];
#pragma unroll
        for (int mf = 0; mf < 4; ++mf)
          aw[mf] = ld8_g(wqkv + (size_t)(512 + h * 64 + mf * 16 + lo) * 128 + kf * 32 + hi * 8);
#pragma unroll
        for (int nf = 0; nf < 2; ++nf)
          bt[nf] = ld8_g(&tw[(qrow + nf * 16 + lo) * 128 + kf * 32 + hi * 8]);
#pragma unroll
        for (int mf = 0; mf < 4; ++mf)
#pragma unroll
          for (int nf = 0; nf < 2; ++nf)
            kacc[mf][nf] = __builtin_amdgcn_mfma_f32_16x16x32_bf16(aw[mf], bt[nf], kacc[mf][nf], 0, 0, 0);
      }
#pragma unroll
      for (int mf = 0; mf < 4; ++mf)
#pragma unroll
        for (int nf = 0; nf < 2; ++nf)
          *(short4v*)&Klds[(qrow + nf * 16 + lo) * KPAD + mf * 16 + hi * 4] = pk4(kacc[mf][nf]);
    }
    /* V stage */
    {
      f32x4 vacc[2][4];
#pragma unroll
      for (int mf = 0; mf < 2; ++mf)
#pragma unroll
        for (int nf = 0; nf < 4; ++nf) vacc[mf][nf] = (f32x4){0.f,0.f,0.f,0.f};
#pragma unroll
      for (int kf = 0; kf < 4; ++kf) {
        short8 at[2], bw[4];
#pragma unroll
        for (int mf = 0; mf < 2; ++mf)
          at[mf] = ld8_g(&tw[(qrow + mf * 16 + lo) * 128 + kf * 32 + hi * 8]);
#pragma unroll
        for (int nf = 0; nf < 4; ++nf)
          bw[nf] = ld8_g(wqkv + (size_t)(1024 + h * 64 + nf * 16 + lo) * 128 + kf * 32 + hi * 8);
#pragma unroll
        for (int mf = 0; mf < 2; ++mf)
#pragma unroll
          for (int nf = 0; nf < 4; ++nf)
            vacc[mf][nf] = __builtin_amdgcn_mfma_f32_16x16x32_bf16(at[mf], bw[nf], vacc[mf][nf], 0, 0, 0);
      }
#pragma unroll
      for (int mf = 0; mf < 2; ++mf)
#pragma unroll
        for (int nf = 0; nf < 4; ++nf)
          *(short4v*)&VT[(nf * 16 + lo) * VPAD + qrow + mf * 16 + hi * 4] = pk4(vacc[mf][nf]);
    }
    /* Q stage */
    {
      f32x4 qacc[4][2];
#pragma unroll
      for (int mf = 0; mf < 4; ++mf)
#pragma unroll
        for (int nf = 0; nf < 2; ++nf) qacc[mf][nf] = (f32x4){0.f,0.f,0.f,0.f};
#pragma unroll
      for (int kf = 0; kf < 4; ++kf) {
        short8 aw[4], bt[2];
#pragma unroll
        for (int mf = 0; mf < 4; ++mf)
          aw[mf] = ld8_g(wqkv + (size_t)(h * 64 + mf * 16 + lo) * 128 + kf * 32 + hi * 8);
#pragma unroll
        for (int nf = 0; nf < 2; ++nf)
          bt[nf] = ld8_g(&tw[(qrow + nf * 16 + lo) * 128 + kf * 32 + hi * 8]);
#pragma unroll
        for (int mf = 0; mf < 4; ++mf)
#pragma unroll
          for (int nf = 0; nf < 2; ++nf)
            qacc[mf][nf] = __builtin_amdgcn_mfma_f32_16x16x32_bf16(aw[mf], bt[nf], qacc[mf][nf], 0, 0, 0);
      }
#pragma unroll
      for (int mf = 0; mf < 4; ++mf)
#pragma unroll
        for (int nf = 0; nf < 2; ++nf)
          *(short4v*)&QP[(nf * 16 + lo) * KPAD + mf * 16 + hi * 4] = pk4(qacc[mf][nf] * 0.125f);
    }
    __syncthreads();

    short8 Qb[2][2];
#pragma unroll
    for (int nf = 0; nf < 2; ++nf)
#pragma unroll
      for (int kf = 0; kf < 2; ++kf)
        Qb[nf][kf] = ld8_lds(&QP[(nf * 16 + lo) * KPAD + kf * 32 + hi * 8]);

    f32x4 Ot[4][2];
#pragma unroll
    for (int mf = 0; mf < 4; ++mf)
#pragma unroll
      for (int nf = 0; nf < 2; ++nf) Ot[mf][nf] = (f32x4){0.f,0.f,0.f,0.f};
    float mrow[2] = {-INFINITY, -INFINITY};
    float lrow[2] = {0.f, 0.f};

    for (int ck = 0; ck < 4; ++ck) {
      f32x4 sacc[4][2];
#pragma unroll
      for (int mf = 0; mf < 4; ++mf)
#pragma unroll
        for (int nf = 0; nf < 2; ++nf) sacc[mf][nf] = (f32x4){0.f,0.f,0.f,0.f};
      short8 ka[4][2];
#pragma unroll
      for (int mf = 0; mf < 4; ++mf)
#pragma unroll
        for (int kf = 0; kf < 2; ++kf)
          ka[mf][kf] = ld8_lds(&Klds[(ck * 64 + mf * 16 + lo) * KPAD + kf * 32 + hi * 8]);
#pragma unroll
      for (int mf = 0; mf < 4; ++mf)
#pragma unroll
        for (int nf = 0; nf < 2; ++nf)
#pragma unroll
          for (int kf = 0; kf < 2; ++kf)
            sacc[mf][nf] = __builtin_amdgcn_mfma_f32_16x16x32_bf16(ka[mf][kf], Qb[nf][kf], sacc[mf][nf], 0, 0, 0);

#pragma unroll
      for (int nf = 0; nf < 2; ++nf) {
        float cmax = -INFINITY;
#pragma unroll
        for (int mf = 0; mf < 4; ++mf)
#pragma unroll
          for (int r = 0; r < 4; ++r) cmax = fmaxf(cmax, sacc[mf][nf][r]);
        cmax = fmaxf(cmax, __shfl_xor(cmax, 16));
        cmax = fmaxf(cmax, __shfl_xor(cmax, 32));
        float mnew = fmaxf(mrow[nf], cmax);
        float corr = __expf(mrow[nf] - mnew);
        float ps = 0.f;
#pragma unroll
        for (int mf = 0; mf < 4; ++mf)
#pragma unroll
          for (int r = 0; r < 4; ++r) {
            float e = __expf(sacc[mf][nf][r] - mnew);
            sacc[mf][nf][r] = e; ps += e;
          }
        ps += __shfl_xor(ps, 16);
        ps += __shfl_xor(ps, 32);
        lrow[nf] = lrow[nf] * corr + ps;
        mrow[nf] = mnew;
#pragma unroll
        for (int mf = 0; mf < 4; ++mf) Ot[mf][nf] *= corr;
      }
#pragma unroll
      for (int mf = 0; mf < 4; ++mf)
#pragma unroll
        for (int nf = 0; nf < 2; ++nf)
          *(short4v*)&QP[(nf * 16 + lo) * KPAD + mf * 16 + hi * 4] = pk4(sacc[mf][nf]);
      short8 pb[2][2], va[4][2];
#pragma unroll
      for (int nf = 0; nf < 2; ++nf)
#pragma unroll
        for (int kf = 0; kf < 2; ++kf)
          pb[nf][kf] = ld8_lds(&QP[(nf * 16 + lo) * KPAD + kf * 32 + hi * 8]);
#pragma unroll
      for (int mf = 0; mf < 4; ++mf)
#pragma unroll
        for (int kf = 0; kf < 2; ++kf)
          va[mf][kf] = ld8_lds(&VT[(mf * 16 + lo) * VPAD + ck * 64 + kf * 32 + hi * 8]);
#pragma unroll
      for (int mf = 0; mf < 4; ++mf)
#pragma unroll
        for (int nf = 0; nf < 2; ++nf)
#pragma unroll
          for (int kf = 0; kf < 2; ++kf)
            Ot[mf][nf] = __builtin_amdgcn_mfma_f32_16x16x32_bf16(va[mf][kf], pb[nf][kf], Ot[mf][nf], 0, 0, 0);
    }

#pragma unroll
    for (int nf = 0; nf < 2; ++nf) {
      float inv = 1.f / lrow[nf];
#pragma unroll
      for (int mf = 0; mf < 4; ++mf)
        *(short4v*)&QP[(nf * 16 + lo) * KPAD + mf * 16 + hi * 4] = pk4(Ot[mf][nf] * inv);
    }
    short8 Ob[2][2];
#pragma unroll
    for (int nf = 0; nf < 2; ++nf)
#pragma unroll
      for (int kf = 0; kf < 2; ++kf)
        Ob[nf][kf] = ld8_lds(&QP[(nf * 16 + lo) * KPAD + kf * 32 + hi * 8]);
#pragma unroll
    for (int kf = 0; kf < 2; ++kf) {
      short8 aw[8];
#pragma unroll
      for (int mf = 0; mf < 8; ++mf)
        aw[mf] = ld8_g(wout + (size_t)(mf * 16 + lo) * 512 + h * 64 + kf * 32 + hi * 8);
#pragma unroll
      for (int mf = 0; mf < 8; ++mf)
#pragma unroll
        for (int nf = 0; nf < 2; ++nf)
          pacc[mf][nf] = __builtin_amdgcn_mfma_f32_16x16x32_bf16(aw[mf], Ob[nf][kf], pacc[mf][nf], 0, 0, 0);
    }
  }

#pragma unroll
  for (int mf = 0; mf < 8; ++mf)
#pragma unroll
    for (int nf = 0; nf < 2; ++nf)
      *(short4v*)&po[((size_t)win * NTOK + qrow + nf * 16 + lo) * 128 + mf * 16 + hi * 4] = pk4(pacc[mf][nf]);
}

/* Gather finalize: thread = (pixel, 32-ch quarter); loops 50 windows. */
__global__ void k_final(const float* __restrict__ x, const unsigned short* __restrict__ po,
                        const int* __restrict__ keep, const float* __restrict__ bout,
                        float* __restrict__ out) {
  __shared__ int kp[2 * NKEEP];
  int tid = threadIdx.x;
  int gid = blockIdx.x * 256 + tid;
  int chq = gid & 3, pix = gid >> 2;
  int b = pix >> 16, pb = pix & 65535, y = pb >> 8, xx = pb & 255;
  if (tid < 2 * NKEEP) kp[tid] = keep[b * 2 * NKEEP + tid];
  __syncthreads();
  float acc[32];
#pragma unroll
  for (int i = 0; i < 32; ++i) acc[i] = 0.f;
  float cnt = 0.f;
  for (int w = 0; w < NKEEP; ++w) {
    int dy = y - kp[2 * w], dx = xx - kp[2 * w + 1];
    if ((unsigned)dy < 16u && (unsigned)dx < 16u) {
      cnt += 1.f;
      const unsigned short* pp = po + ((size_t)(b * NKEEP + w) * NTOK + dy * 16 + dx) * 128 + chq * 32;
#pragma unroll
      for (int k2 = 0; k2 < 4; ++k2) {
        short8 v = ld8_g(pp + k2 * 8);
#pragma unroll
        for (int j = 0; j < 8; ++j) {
          union { unsigned u; float f; } cv;
          cv.u = ((unsigned)(unsigned short)v[j]) << 16;
          acc[k2 * 8 + j] += cv.f;
        }
      }
    }
  }
  size_t base = (size_t)pix * 128 + chq * 32;
  float inv = 1.f / (cnt + 1e-10f);
#pragma unroll
  for (int i = 0; i < 32; ++i)
    out[base + i] = x[base + i] + (acc[i] + cnt * bout[chq * 32 + i]) * inv;
}

extern "C" void kernel_launch(void* const* d_in, const int* in_sizes, int n_in,
                              void* d_out, int out_size, void* d_ws, size_t ws_size,
                              hipStream_t stream) {
  const float* x    = (const float*)d_in[0];
  const float* prob = (const float*)d_in[1];
  const float* fixw = (const float*)d_in[2];
  const float* wqkv = (const float*)d_in[3];
  const float* wout = (const float*)d_in[4];
  const float* bout = (const float*)d_in[5];
  float* out = (float*)d_out;
  float* ws  = (float*)d_ws;
  if (ws_size < WS_FLOATS * sizeof(float)) return;  /* need ~27.3 MB scratch */

  float* ent  = ws + OFF_ENT;
  float* scp  = ws + OFF_SCORE;
  int*   keep = (int*)(ws + OFF_KEEP);
  unsigned short* wqkv_bf = (unsigned short*)(ws + OFF_WQKV);
  unsigned short* wout_bf = (unsigned short*)(ws + OFF_WOUT);
  unsigned short* tokbf   = (unsigned short*)(ws + OFF_TOKBF);
  unsigned short* po      = (unsigned short*)(ws + OFF_PO);

  k_entropy<<<256, 256, 0, stream>>>(prob, ent);
  k_score<<<(NB * SCPAD + 255) / 256, 256, 0, stream>>>(ent, fixw, scp);
  k_wcvt<<<1024, 256, 0, stream>>>(wqkv, wout, wqkv_bf, wout_bf);
  k_nms<<<NB, 64, 0, stream>>>(scp, keep);
  k_toks<<<NWTOT, 256, 0, stream>>>(x, keep, tokbf);
  k_attn<<<NWTOT, 512, 0, stream>>>(tokbf, wqkv_bf, wout_bf, po);
  k_final<<<NB * 65536 * 4 / 256, 256, 0, stream>>>(x, po, keep, bout, out);
}